// Round 2
// baseline (4421.519 us; speedup 1.0000x reference)
//
#include <hip/hip_runtime.h>
#include <hip/hip_bf16.h>
#include <math.h>

// Problem dims
constexpr int NN  = 8192;
constexpr int EE  = 262144;
constexpr int IN  = 3000;
constexpr int HID = 256;
constexpr int OUT = 64;

// Output offsets (floats) in d_out: (h2, h3, ret, ret_a, h2, h2_a)
constexpr long O_H2   = 0;
constexpr long O_H3   = 524288;          // 8192*64
constexpr long O_RET  = 25100288;        // + 8192*3000
constexpr long O_RETA = 25116672;        // + 8192*2
constexpr long O_H2B  = 25133056;        // + 8192*2
constexpr long O_H2A  = 25657344;        // + 8192*64

// ---------------- generic guarded f32 SGEMM: C[M,N] = A[M,K] @ B[K,N] (+bias) ----------------
#define TS 64
#define KS 16
__global__ __launch_bounds__(256) void sgemm(const float* __restrict__ A,
                                             const float* __restrict__ B,
                                             const float* __restrict__ bias,
                                             float* __restrict__ C,
                                             int M, int N, int K) {
    __shared__ float As[KS][TS + 1];  // As[k][m]
    __shared__ float Bs[KS][TS + 1];  // Bs[k][n]
    int tid = threadIdx.x;
    int tx = tid & 15, ty = tid >> 4;
    int row0 = blockIdx.y * TS;
    int col0 = blockIdx.x * TS;
    float acc[4][4] = {};
    for (int k0 = 0; k0 < K; k0 += KS) {
        {   // A tile: 64 rows x 16 k
            int r  = tid >> 2;
            int kk = (tid & 3) * 4;
            int gr = row0 + r;
#pragma unroll
            for (int i = 0; i < 4; ++i) {
                int gk = k0 + kk + i;
                float v = (gr < M && gk < K) ? A[(long)gr * K + gk] : 0.0f;
                As[kk + i][r] = v;
            }
        }
        {   // B tile: 16 k x 64 n
            int kk = tid >> 4;
            int c  = (tid & 15) * 4;
            int gk = k0 + kk;
#pragma unroll
            for (int i = 0; i < 4; ++i) {
                int gc = col0 + c + i;
                float v = (gk < K && gc < N) ? B[(long)gk * N + gc] : 0.0f;
                Bs[kk][c + i] = v;
            }
        }
        __syncthreads();
#pragma unroll
        for (int k = 0; k < KS; ++k) {
            float a[4], b[4];
#pragma unroll
            for (int i = 0; i < 4; ++i) a[i] = As[k][ty * 4 + i];
#pragma unroll
            for (int j = 0; j < 4; ++j) b[j] = Bs[k][tx * 4 + j];
#pragma unroll
            for (int i = 0; i < 4; ++i)
#pragma unroll
                for (int j = 0; j < 4; ++j) acc[i][j] += a[i] * b[j];
        }
        __syncthreads();
    }
#pragma unroll
    for (int i = 0; i < 4; ++i) {
        int gr = row0 + ty * 4 + i;
        if (gr >= M) continue;
#pragma unroll
        for (int j = 0; j < 4; ++j) {
            int gc = col0 + tx * 4 + j;
            if (gc >= N) continue;
            float v = acc[i][j];
            if (bias) v += bias[gc];
            C[(long)gr * N + gc] = v;
        }
    }
}

// ---------------- attention coefficients: a_src[n]=h[n]·att_src, a_dst[n]=h[n]·att_dst -------
__global__ void attn_coeff(const float* __restrict__ h, const float* __restrict__ att_src,
                           const float* __restrict__ att_dst, float* __restrict__ a_src,
                           float* __restrict__ a_dst) {
    int wave = threadIdx.x >> 6;
    int lane = threadIdx.x & 63;
    int n = blockIdx.x * 4 + wave;
    float s1 = 0.f, s2 = 0.f;
#pragma unroll
    for (int c = 0; c < 4; ++c) {
        int j = c * 64 + lane;
        float hv = h[(long)n * HID + j];
        s1 += hv * att_src[j];
        s2 += hv * att_dst[j];
    }
    for (int off = 32; off > 0; off >>= 1) {
        s1 += __shfl_down(s1, off);
        s2 += __shfl_down(s2, off);
    }
    if (lane == 0) { a_src[n] = s1; a_dst[n] = s2; }
}

// ---------------- edge kernels -------------------------------------------------------------
__device__ __forceinline__ unsigned enc_f32(float f) {
    unsigned u = __float_as_uint(f);
    return (u & 0x80000000u) ? ~u : (u | 0x80000000u);
}
__device__ __forceinline__ float dec_f32(unsigned u) {
    return __uint_as_float((u & 0x80000000u) ? (u ^ 0x80000000u) : ~u);
}

__global__ void edge_logits(const int* __restrict__ src, const int* __restrict__ dst,
                            const float* __restrict__ a_src, const float* __restrict__ a_dst,
                            float* __restrict__ e, unsigned* __restrict__ m_enc) {
    int i = blockIdx.x * 256 + threadIdx.x;
    if (i >= EE) return;
    float x = a_src[src[i]] + a_dst[dst[i]];
    x = x > 0.f ? x : 0.2f * x;          // leaky_relu 0.2
    e[i] = x;
    atomicMax(&m_enc[dst[i]], enc_f32(x));
}

__global__ void edge_softmax(const int* __restrict__ dst, float* __restrict__ e,
                             const unsigned* __restrict__ m_enc, float* __restrict__ z) {
    int i = blockIdx.x * 256 + threadIdx.x;
    if (i >= EE) return;
    int d = dst[i];
    float p = expf(e[i] - dec_f32(m_enc[d]));
    e[i] = p;                            // overwrite e with p
    atomicAdd(&z[d], p);
}

__global__ void edge_aggregate(const int* __restrict__ src, const int* __restrict__ dst,
                               const float* __restrict__ p, const float* __restrict__ z,
                               const float* __restrict__ h, float* __restrict__ gat) {
    int e = blockIdx.x * 4 + (threadIdx.x >> 6);
    int lane = threadIdx.x & 63;
    int s = src[e], d = dst[e];
    float alpha = p[e] / (z[d] + 1e-16f);
    const float4 hv = *reinterpret_cast<const float4*>(&h[(long)s * HID + lane * 4]);
    float* gp = &gat[(long)d * HID + lane * 4];
    atomicAdd(gp + 0, alpha * hv.x);
    atomicAdd(gp + 1, alpha * hv.y);
    atomicAdd(gp + 2, alpha * hv.z);
    atomicAdd(gp + 3, alpha * hv.w);
}

// ---------------- misc elementwise ----------------------------------------------------------
__global__ void elu_inplace(float* __restrict__ x, long n) {
    for (long i = (long)blockIdx.x * blockDim.x + threadIdx.x; i < n;
         i += (long)gridDim.x * blockDim.x) {
        float v = x[i];
        x[i] = v > 0.f ? v : expm1f(v);
    }
}

// ---------------- batchnorm ----------------------------------------------------------------
__global__ void bn_partial(const float* __restrict__ zd, float* __restrict__ s,
                           float* __restrict__ sq) {
    int t = threadIdx.x;  // column
    float a = 0.f, b = 0.f;
    int r0 = blockIdx.x * 128;
    for (int r = r0; r < r0 + 128; ++r) {
        float v = zd[(long)r * HID + t];
        a += v;
        b += v * v;
    }
    atomicAdd(&s[t], a);
    atomicAdd(&sq[t], b);
}

__global__ void bn_finalize(const float* __restrict__ s, const float* __restrict__ sq,
                            const float* __restrict__ gamma, const float* __restrict__ beta,
                            float* __restrict__ scale, float* __restrict__ shift) {
    int t = threadIdx.x;
    float mean = s[t] / (float)NN;
    float var  = sq[t] / (float)NN - mean * mean;
    float sc   = gamma[t] * rsqrtf(var + 1e-5f);
    scale[t] = sc;
    shift[t] = beta[t] - mean * sc;
}

__global__ void bn_apply_elu(float* __restrict__ zd, const float* __restrict__ scale,
                             const float* __restrict__ shift) {
    for (long i = (long)blockIdx.x * blockDim.x + threadIdx.x; i < (long)NN * HID;
         i += (long)gridDim.x * blockDim.x) {
        int c = (int)(i & 255);
        float v = zd[i] * scale[c] + shift[c];
        zd[i] = v > 0.f ? v : expm1f(v);
    }
}

// ---------------- readout ------------------------------------------------------------------
__global__ void row_sum(const float* __restrict__ gn, float* __restrict__ rs) {
    int r = blockIdx.x;
    float s = 0.f;
    for (int c = threadIdx.x; c < NN; c += 256) s += gn[(long)r * NN + c];
    __shared__ float red[256];
    red[threadIdx.x] = s;
    __syncthreads();
    for (int o = 128; o > 0; o >>= 1) {
        if (threadIdx.x < o) red[threadIdx.x] += red[threadIdx.x + o];
        __syncthreads();
    }
    if (threadIdx.x == 0) rs[r] = red[0];
}

__global__ void pack_hcat(const float* __restrict__ h2, const float* __restrict__ h2a,
                          float* __restrict__ Hcat) {
    int i = blockIdx.x * 256 + threadIdx.x;   // 8192*128 total
    int r = i >> 7, c = i & 127;
    Hcat[i] = (c < 64) ? h2[(long)r * 64 + c] : h2a[(long)r * 64 + (c - 64)];
}

__global__ void readout_norm(const float* __restrict__ vsum, const float* __restrict__ rowsum,
                             float* __restrict__ g, float* __restrict__ ga) {
    int r = blockIdx.x;
    int w = threadIdx.x >> 6, lane = threadIdx.x & 63;
    float v = vsum[(long)r * 128 + w * 64 + lane] / rowsum[r];
    float sq = v * v;
    for (int off = 32; off > 0; off >>= 1) sq += __shfl_xor(sq, off);
    float nrm = fmaxf(sqrtf(sq), 1e-12f);
    float out = 1.0f / (1.0f + expf(-(v / nrm)));
    (w == 0 ? g : ga)[(long)r * 64 + lane] = out;
}

// ---------------- discriminator ------------------------------------------------------------
__global__ void disc_kernel(const float* __restrict__ h2, const float* __restrict__ h2a,
                            const float* __restrict__ g, const float* __restrict__ ga,
                            const float* __restrict__ W, const float* __restrict__ b,
                            float* __restrict__ ret, float* __restrict__ reta) {
    int n = blockIdx.x;
    int w = threadIdx.x >> 6, lane = threadIdx.x & 63;  // lane = d
    const float* c = (w == 0) ? g : ga;
    float u = 0.f;
#pragma unroll 8
    for (int e = 0; e < 64; ++e) u += W[lane * 64 + e] * c[(long)n * 64 + e];
    float hp = ((w == 0) ? h2 : h2a)[(long)n * 64 + lane];
    float hm = ((w == 0) ? h2a : h2)[(long)n * 64 + lane];
    float t1 = hp * u, t2 = hm * u;
    for (int off = 32; off > 0; off >>= 1) {
        t1 += __shfl_xor(t1, off);
        t2 += __shfl_xor(t2, off);
    }
    if (lane == 0) {
        float bb = b[0];
        if (w == 0) { ret[n * 2] = t1 + bb;  ret[n * 2 + 1] = t2 + bb; }
        else        { reta[n * 2] = t1 + bb; reta[n * 2 + 1] = t2 + bb; }
    }
}

__global__ void copy_h2(const float* __restrict__ h2, const float* __restrict__ h2a,
                        float* __restrict__ out) {
    int i = blockIdx.x * 256 + threadIdx.x;   // 524288 total
    float v = h2[i], va = h2a[i];
    out[O_H2 + i]  = v;
    out[O_H2B + i] = v;
    out[O_H2A + i] = va;
}

// ---------------- driver -------------------------------------------------------------------
extern "C" void kernel_launch(void* const* d_in, const int* in_sizes, int n_in,
                              void* d_out, int out_size, void* d_ws, size_t ws_size,
                              hipStream_t stream) {
    const float* feat    = (const float*)d_in[0];
    const float* feat_a  = (const float*)d_in[1];
    const float* gneigh  = (const float*)d_in[2];
    const float* W1      = (const float*)d_in[3];
    const float* att_src = (const float*)d_in[4];
    const float* att_dst = (const float*)d_in[5];
    const float* W2      = (const float*)d_in[6];
    const float* Wd1     = (const float*)d_in[7];
    const float* bd1     = (const float*)d_in[8];
    const float* gamma   = (const float*)d_in[9];
    const float* beta    = (const float*)d_in[10];
    const float* Wd2     = (const float*)d_in[11];
    const float* bd2     = (const float*)d_in[12];
    const float* disc_W  = (const float*)d_in[13];
    const float* disc_b  = (const float*)d_in[14];
    const int*   eidx    = (const int*)d_in[15];
    const int*   src = eidx;
    const int*   dst = eidx + EE;
    float* out = (float*)d_out;

    // workspace layout (floats)
    float* w = (float*)d_ws;
    float* h_buf   = w;                       // 2097152
    float* gat_buf = h_buf + 2097152;         // 2097152
    float* zdec    = gat_buf + 2097152;       // 2097152 (later reused: Hcat | vsum)
    float* h2      = zdec + 2097152;          // 524288
    float* h2a     = h2 + 524288;             // 524288
    float* gbuf    = h2a + 524288;            // 524288
    float* gabuf   = gbuf + 524288;           // 524288
    float* asrc    = gabuf + 524288;          // 8192
    float* adst    = asrc + 8192;             // 8192
    float* ebuf    = adst + 8192;             // 262144
    unsigned* menc = (unsigned*)(ebuf + 262144); // 8192
    float* zsum    = (float*)(menc + 8192);   // 8192
    float* rowsum  = zsum + 8192;             // 8192
    float* bnsum   = rowsum + 8192;           // 256
    float* bnsq    = bnsum + 256;             // 256
    float* scale   = bnsq + 256;              // 256
    float* shift   = scale + 256;             // 256

    auto encode_pass = [&](const float* x, float* h2_out) {
        hipMemsetAsync(menc, 0, 8192 * 4, stream);
        hipMemsetAsync(zsum, 0, 8192 * 4, stream);
        hipMemsetAsync(gat_buf, 0, (size_t)2097152 * 4, stream);
        // h = x @ W1
        sgemm<<<dim3(4, 128), 256, 0, stream>>>(x, W1, nullptr, h_buf, NN, HID, IN);
        attn_coeff<<<2048, 256, 0, stream>>>(h_buf, att_src, att_dst, asrc, adst);
        edge_logits<<<EE / 256, 256, 0, stream>>>(src, dst, asrc, adst, ebuf, menc);
        edge_softmax<<<EE / 256, 256, 0, stream>>>(dst, ebuf, menc, zsum);
        edge_aggregate<<<EE / 4, 256, 0, stream>>>(src, dst, ebuf, zsum, h_buf, gat_buf);
        elu_inplace<<<2048, 256, 0, stream>>>(gat_buf, (long)NN * HID);
        // h2 = h1 @ W2
        sgemm<<<dim3(1, 128), 256, 0, stream>>>(gat_buf, W2, nullptr, h2_out, NN, OUT, HID);
    };

    encode_pass(feat, h2);
    encode_pass(feat_a, h2a);

    // ---- decoder: h3 = elu(BN(h2 @ Wd1 + bd1)) @ Wd2 + bd2
    sgemm<<<dim3(4, 128), 256, 0, stream>>>(h2, Wd1, bd1, zdec, NN, HID, OUT);
    hipMemsetAsync(bnsum, 0, 512 * 4, stream);  // bnsum + bnsq contiguous
    bn_partial<<<64, 256, 0, stream>>>(zdec, bnsum, bnsq);
    bn_finalize<<<1, 256, 0, stream>>>(bnsum, bnsq, gamma, beta, scale, shift);
    bn_apply_elu<<<2048, 256, 0, stream>>>(zdec, scale, shift);
    sgemm<<<dim3(47, 128), 256, 0, stream>>>(zdec, Wd2, bd2, out + O_H3, NN, IN, HID);

    // ---- readout (both graphs share graph_neigh; one GEMM with concat [h2|h2a])
    float* Hcat = zdec;                 // reuse
    float* vsum = zdec + 1048576;
    pack_hcat<<<4096, 256, 0, stream>>>(h2, h2a, Hcat);
    row_sum<<<8192, 256, 0, stream>>>(gneigh, rowsum);
    sgemm<<<dim3(2, 128), 256, 0, stream>>>(gneigh, Hcat, nullptr, vsum, NN, 128, NN);
    readout_norm<<<8192, 128, 0, stream>>>(vsum, rowsum, gbuf, gabuf);

    // ---- discriminator
    disc_kernel<<<8192, 128, 0, stream>>>(h2, h2a, gbuf, gabuf, disc_W, disc_b,
                                          out + O_RET, out + O_RETA);

    // ---- copy h2 outputs (slots 0, 4, 5)
    copy_h2<<<2048, 256, 0, stream>>>(h2, h2a, out);
}

// Round 3
// 2965.167 us; speedup vs baseline: 1.4912x; 1.4912x over previous
//
#include <hip/hip_runtime.h>
#include <hip/hip_bf16.h>
#include <math.h>

// Problem dims
constexpr int NN  = 8192;
constexpr int EE  = 262144;
constexpr int IN  = 3000;
constexpr int HID = 256;
constexpr int OUT = 64;

// Output offsets (floats) in d_out: (h2, h3, ret, ret_a, h2, h2_a)
constexpr long O_H2   = 0;
constexpr long O_H3   = 524288;          // 8192*64
constexpr long O_RET  = 25100288;        // + 8192*3000
constexpr long O_RETA = 25116672;        // + 8192*2
constexpr long O_H2B  = 25133056;        // + 8192*2
constexpr long O_H2A  = 25657344;        // + 8192*64

// ---------------- sgemm_v2: C[M,N] = A[M,K]@B[K,N] (+bias) --------------------------------
// 64x64 tile, KS=32, 4x4 micro, 256 threads. M must be multiple of 64.
// LDS stride 68 floats = 272 B (16B-aligned) -> ds_read_b128 on fragments, 2-way-max bank alias.
// blockIdx.z = split-K chunk; atomic_out=1 -> atomicAdd epilogue (C pre-zeroed, no bias).
__global__ __launch_bounds__(256) void sgemm_v2(const float* __restrict__ A,
                                                const float* __restrict__ B,
                                                const float* __restrict__ bias,
                                                float* __restrict__ C,
                                                int M, int N, int K,
                                                int kchunk, int atomic_out) {
    __shared__ float As[32][68];   // [k][row]
    __shared__ float Bs[32][68];   // [k][col]
    int t = threadIdx.x;
    int row0 = blockIdx.y * 64;
    int col0 = blockIdx.x * 64;
    int kbeg = blockIdx.z * kchunk;
    int kend = min(K, kbeg + kchunk);

    int ar  = t & 63;            // A row within tile
    int akq = (t >> 6) * 8;      // A k-offset (wave id * 8)
    int bkr = t >> 3;            // B k-row 0..31
    int bcq = (t & 7) * 8;       // B col-offset
    const float* Arow = A + (long)(row0 + ar) * K;
    int tx4 = (t & 15) * 4, ty4 = (t >> 4) * 4;

    float acc[4][4] = {};
    for (int k0 = kbeg; k0 < kend; k0 += 32) {
        // ---- A tile: 64 rows x 32 k
        if (k0 + 32 <= kend) {
            float4 v0 = *reinterpret_cast<const float4*>(Arow + k0 + akq);
            float4 v1 = *reinterpret_cast<const float4*>(Arow + k0 + akq + 4);
            As[akq+0][ar]=v0.x; As[akq+1][ar]=v0.y; As[akq+2][ar]=v0.z; As[akq+3][ar]=v0.w;
            As[akq+4][ar]=v1.x; As[akq+5][ar]=v1.y; As[akq+6][ar]=v1.z; As[akq+7][ar]=v1.w;
        } else {
#pragma unroll
            for (int i = 0; i < 8; ++i) {
                int gk = k0 + akq + i;
                As[akq+i][ar] = (gk < kend) ? Arow[gk] : 0.f;
            }
        }
        // ---- B tile: 32 k x 64 n
        {
            int gk = k0 + bkr;
            int gc = col0 + bcq;
            if (gk < kend && gc + 8 <= N) {
                const float* Bp = B + (long)gk * N + gc;
                *reinterpret_cast<float4*>(&Bs[bkr][bcq])   = *reinterpret_cast<const float4*>(Bp);
                *reinterpret_cast<float4*>(&Bs[bkr][bcq+4]) = *reinterpret_cast<const float4*>(Bp + 4);
            } else {
#pragma unroll
                for (int i = 0; i < 8; ++i) {
                    int c = gc + i;
                    Bs[bkr][bcq+i] = (gk < kend && c < N) ? B[(long)gk * N + c] : 0.f;
                }
            }
        }
        __syncthreads();
#pragma unroll
        for (int k = 0; k < 32; ++k) {
            float4 a = *reinterpret_cast<const float4*>(&As[k][ty4]);
            float4 b = *reinterpret_cast<const float4*>(&Bs[k][tx4]);
            float av[4] = {a.x, a.y, a.z, a.w};
            float bv[4] = {b.x, b.y, b.z, b.w};
#pragma unroll
            for (int i = 0; i < 4; ++i)
#pragma unroll
                for (int j = 0; j < 4; ++j) acc[i][j] += av[i] * bv[j];
        }
        __syncthreads();
    }
#pragma unroll
    for (int i = 0; i < 4; ++i) {
        int gr = row0 + ty4 + i;
#pragma unroll
        for (int j = 0; j < 4; ++j) {
            int gc = col0 + tx4 + j;
            if (gc < N) {
                long idx = (long)gr * N + gc;
                if (atomic_out) atomicAdd(&C[idx], acc[i][j]);
                else            C[idx] = acc[i][j] + (bias ? bias[gc] : 0.f);
            }
        }
    }
}

// ---------------- readout GEMM: vsum[8192,128] = gn[8192,8192] @ Hcat[8192,128] -----------
// 128x128 tile, 8x8 micro, KS=32, split-K=8 (kchunk 1024), fused row-sum of gn.
// vsum & rowsum must be pre-zeroed (atomicAdd epilogue).
__global__ __launch_bounds__(256) void readout_gemm(const float* __restrict__ gn,
                                                    const float* __restrict__ Hc,
                                                    float* __restrict__ vsum,
                                                    float* __restrict__ rowsum) {
    __shared__ float As[32][132];  // [k][row 0..127]
    __shared__ float Bs[32][132];  // [k][col 0..127]
    __shared__ float rs[2][128];
    int t = threadIdx.x;
    int row0 = blockIdx.x * 128;
    int kbeg = blockIdx.y * 1024;

    int ar  = t & 127;            // A row
    int akq = (t >> 7) * 16;      // 0 or 16
    const float* Arow = gn + (long)(row0 + ar) * NN;
    int bkr = t >> 3;             // 0..31
    int bcq = (t & 7) * 16;       // 0..112
    int tx8 = (t & 15) * 8, ty8 = (t >> 4) * 8;

    float acc[8][8] = {};
    float myrs = 0.f;
    for (int k0 = kbeg; k0 < kbeg + 1024; k0 += 32) {
        // A: 128 rows x 32 k (16 k per thread, 4x float4)
#pragma unroll
        for (int q = 0; q < 4; ++q) {
            float4 v = *reinterpret_cast<const float4*>(Arow + k0 + akq + q * 4);
            As[akq + q*4 + 0][ar] = v.x;
            As[akq + q*4 + 1][ar] = v.y;
            As[akq + q*4 + 2][ar] = v.z;
            As[akq + q*4 + 3][ar] = v.w;
            myrs += v.x + v.y + v.z + v.w;
        }
        // B: 32 k x 128 cols (4x float4 per thread)
        {
            const float* Bp = Hc + (long)(k0 + bkr) * 128 + bcq;
#pragma unroll
            for (int q = 0; q < 4; ++q)
                *reinterpret_cast<float4*>(&Bs[bkr][bcq + q*4]) =
                    *reinterpret_cast<const float4*>(Bp + q*4);
        }
        __syncthreads();
#pragma unroll
        for (int k = 0; k < 32; ++k) {
            float4 a0 = *reinterpret_cast<const float4*>(&As[k][ty8]);
            float4 a1 = *reinterpret_cast<const float4*>(&As[k][ty8 + 4]);
            float4 b0 = *reinterpret_cast<const float4*>(&Bs[k][tx8]);
            float4 b1 = *reinterpret_cast<const float4*>(&Bs[k][tx8 + 4]);
            float av[8] = {a0.x,a0.y,a0.z,a0.w,a1.x,a1.y,a1.z,a1.w};
            float bv[8] = {b0.x,b0.y,b0.z,b0.w,b1.x,b1.y,b1.z,b1.w};
#pragma unroll
            for (int i = 0; i < 8; ++i)
#pragma unroll
                for (int j = 0; j < 8; ++j) acc[i][j] += av[i] * bv[j];
        }
        __syncthreads();
    }
    // fused row-sum (each row covered by 2 threads: akq=0/16)
    rs[t >> 7][ar] = myrs;
    __syncthreads();
    if (t < 128) atomicAdd(&rowsum[row0 + t], rs[0][t] + rs[1][t]);
#pragma unroll
    for (int i = 0; i < 8; ++i) {
        long base = (long)(row0 + ty8 + i) * 128;
#pragma unroll
        for (int j = 0; j < 8; ++j)
            atomicAdd(&vsum[base + tx8 + j], acc[i][j]);
    }
}

// ---------------- attention coefficients ---------------------------------------------------
__global__ void attn_coeff(const float* __restrict__ h, const float* __restrict__ att_src,
                           const float* __restrict__ att_dst, float* __restrict__ a_src,
                           float* __restrict__ a_dst) {
    int wave = threadIdx.x >> 6;
    int lane = threadIdx.x & 63;
    int n = blockIdx.x * 4 + wave;
    float s1 = 0.f, s2 = 0.f;
#pragma unroll
    for (int c = 0; c < 4; ++c) {
        int j = c * 64 + lane;
        float hv = h[(long)n * HID + j];
        s1 += hv * att_src[j];
        s2 += hv * att_dst[j];
    }
    for (int off = 32; off > 0; off >>= 1) {
        s1 += __shfl_down(s1, off);
        s2 += __shfl_down(s2, off);
    }
    if (lane == 0) { a_src[n] = s1; a_dst[n] = s2; }
}

// ---------------- edge kernels -------------------------------------------------------------
__device__ __forceinline__ unsigned enc_f32(float f) {
    unsigned u = __float_as_uint(f);
    return (u & 0x80000000u) ? ~u : (u | 0x80000000u);
}
__device__ __forceinline__ float dec_f32(unsigned u) {
    return __uint_as_float((u & 0x80000000u) ? (u ^ 0x80000000u) : ~u);
}

__global__ void edge_logits(const int* __restrict__ src, const int* __restrict__ dst,
                            const float* __restrict__ a_src, const float* __restrict__ a_dst,
                            float* __restrict__ e, unsigned* __restrict__ m_enc) {
    int i = blockIdx.x * 256 + threadIdx.x;
    if (i >= EE) return;
    float x = a_src[src[i]] + a_dst[dst[i]];
    x = x > 0.f ? x : 0.2f * x;          // leaky_relu 0.2
    e[i] = x;
    atomicMax(&m_enc[dst[i]], enc_f32(x));
}

__global__ void edge_softmax(const int* __restrict__ dst, float* __restrict__ e,
                             const unsigned* __restrict__ m_enc, float* __restrict__ z) {
    int i = blockIdx.x * 256 + threadIdx.x;
    if (i >= EE) return;
    int d = dst[i];
    float p = expf(e[i] - dec_f32(m_enc[d]));
    e[i] = p;
    atomicAdd(&z[d], p);
}

__global__ void edge_aggregate(const int* __restrict__ src, const int* __restrict__ dst,
                               const float* __restrict__ p, const float* __restrict__ z,
                               const float* __restrict__ h, float* __restrict__ gat) {
    int e = blockIdx.x * 4 + (threadIdx.x >> 6);
    int lane = threadIdx.x & 63;
    int s = src[e], d = dst[e];
    float alpha = p[e] / (z[d] + 1e-16f);
    const float4 hv = *reinterpret_cast<const float4*>(&h[(long)s * HID + lane * 4]);
    float* gp = &gat[(long)d * HID + lane * 4];
    atomicAdd(gp + 0, alpha * hv.x);
    atomicAdd(gp + 1, alpha * hv.y);
    atomicAdd(gp + 2, alpha * hv.z);
    atomicAdd(gp + 3, alpha * hv.w);
}

// ---------------- misc elementwise ----------------------------------------------------------
__global__ void elu_inplace(float* __restrict__ x, long n) {
    for (long i = (long)blockIdx.x * blockDim.x + threadIdx.x; i < n;
         i += (long)gridDim.x * blockDim.x) {
        float v = x[i];
        x[i] = v > 0.f ? v : expm1f(v);
    }
}

// ---------------- batchnorm ----------------------------------------------------------------
__global__ void bn_partial(const float* __restrict__ zd, float* __restrict__ s,
                           float* __restrict__ sq) {
    int t = threadIdx.x;  // column
    float a = 0.f, b = 0.f;
    int r0 = blockIdx.x * 128;
    for (int r = r0; r < r0 + 128; ++r) {
        float v = zd[(long)r * HID + t];
        a += v;
        b += v * v;
    }
    atomicAdd(&s[t], a);
    atomicAdd(&sq[t], b);
}

__global__ void bn_finalize(const float* __restrict__ s, const float* __restrict__ sq,
                            const float* __restrict__ gamma, const float* __restrict__ beta,
                            float* __restrict__ scale, float* __restrict__ shift) {
    int t = threadIdx.x;
    float mean = s[t] / (float)NN;
    float var  = sq[t] / (float)NN - mean * mean;
    float sc   = gamma[t] * rsqrtf(var + 1e-5f);
    scale[t] = sc;
    shift[t] = beta[t] - mean * sc;
}

__global__ void bn_apply_elu(float* __restrict__ zd, const float* __restrict__ scale,
                             const float* __restrict__ shift) {
    for (long i = (long)blockIdx.x * blockDim.x + threadIdx.x; i < (long)NN * HID;
         i += (long)gridDim.x * blockDim.x) {
        int c = (int)(i & 255);
        float v = zd[i] * scale[c] + shift[c];
        zd[i] = v > 0.f ? v : expm1f(v);
    }
}

// ---------------- readout tail -------------------------------------------------------------
__global__ void pack_hcat(const float* __restrict__ h2, const float* __restrict__ h2a,
                          float* __restrict__ Hcat) {
    int i = blockIdx.x * 256 + threadIdx.x;   // 8192*128 total
    int r = i >> 7, c = i & 127;
    Hcat[i] = (c < 64) ? h2[(long)r * 64 + c] : h2a[(long)r * 64 + (c - 64)];
}

__global__ void readout_norm(const float* __restrict__ vsum, const float* __restrict__ rowsum,
                             float* __restrict__ g, float* __restrict__ ga) {
    int r = blockIdx.x;
    int w = threadIdx.x >> 6, lane = threadIdx.x & 63;
    float v = vsum[(long)r * 128 + w * 64 + lane] / rowsum[r];
    float sq = v * v;
    for (int off = 32; off > 0; off >>= 1) sq += __shfl_xor(sq, off);
    float nrm = fmaxf(sqrtf(sq), 1e-12f);
    float out = 1.0f / (1.0f + expf(-(v / nrm)));
    (w == 0 ? g : ga)[(long)r * 64 + lane] = out;
}

// ---------------- discriminator ------------------------------------------------------------
__global__ void disc_kernel(const float* __restrict__ h2, const float* __restrict__ h2a,
                            const float* __restrict__ g, const float* __restrict__ ga,
                            const float* __restrict__ W, const float* __restrict__ b,
                            float* __restrict__ ret, float* __restrict__ reta) {
    int n = blockIdx.x;
    int w = threadIdx.x >> 6, lane = threadIdx.x & 63;  // lane = d
    const float* c = (w == 0) ? g : ga;
    float u = 0.f;
#pragma unroll 8
    for (int e = 0; e < 64; ++e) u += W[lane * 64 + e] * c[(long)n * 64 + e];
    float hp = ((w == 0) ? h2 : h2a)[(long)n * 64 + lane];
    float hm = ((w == 0) ? h2a : h2)[(long)n * 64 + lane];
    float t1 = hp * u, t2 = hm * u;
    for (int off = 32; off > 0; off >>= 1) {
        t1 += __shfl_xor(t1, off);
        t2 += __shfl_xor(t2, off);
    }
    if (lane == 0) {
        float bb = b[0];
        if (w == 0) { ret[n * 2] = t1 + bb;  ret[n * 2 + 1] = t2 + bb; }
        else        { reta[n * 2] = t1 + bb; reta[n * 2 + 1] = t2 + bb; }
    }
}

__global__ void copy_h2(const float* __restrict__ h2, const float* __restrict__ h2a,
                        float* __restrict__ out) {
    int i = blockIdx.x * 256 + threadIdx.x;   // 524288 total
    float v = h2[i], va = h2a[i];
    out[O_H2 + i]  = v;
    out[O_H2B + i] = v;
    out[O_H2A + i] = va;
}

// ---------------- driver -------------------------------------------------------------------
extern "C" void kernel_launch(void* const* d_in, const int* in_sizes, int n_in,
                              void* d_out, int out_size, void* d_ws, size_t ws_size,
                              hipStream_t stream) {
    const float* feat    = (const float*)d_in[0];
    const float* feat_a  = (const float*)d_in[1];
    const float* gneigh  = (const float*)d_in[2];
    const float* W1      = (const float*)d_in[3];
    const float* att_src = (const float*)d_in[4];
    const float* att_dst = (const float*)d_in[5];
    const float* W2      = (const float*)d_in[6];
    const float* Wd1     = (const float*)d_in[7];
    const float* bd1     = (const float*)d_in[8];
    const float* gamma   = (const float*)d_in[9];
    const float* beta    = (const float*)d_in[10];
    const float* Wd2     = (const float*)d_in[11];
    const float* bd2     = (const float*)d_in[12];
    const float* disc_W  = (const float*)d_in[13];
    const float* disc_b  = (const float*)d_in[14];
    const int*   eidx    = (const int*)d_in[15];
    const int*   src = eidx;
    const int*   dst = eidx + EE;
    float* out = (float*)d_out;

    // workspace layout (floats)
    float* w = (float*)d_ws;
    float* h_buf   = w;                       // 2097152
    float* gat_buf = h_buf + 2097152;         // 2097152
    float* zdec    = gat_buf + 2097152;       // 2097152 (later reused: Hcat | vsum)
    float* h2      = zdec + 2097152;          // 524288
    float* h2a     = h2 + 524288;             // 524288
    float* gbuf    = h2a + 524288;            // 524288
    float* gabuf   = gbuf + 524288;           // 524288
    float* asrc    = gabuf + 524288;          // 8192
    float* adst    = asrc + 8192;             // 8192
    float* ebuf    = adst + 8192;             // 262144
    unsigned* menc = (unsigned*)(ebuf + 262144); // 8192
    float* zsum    = (float*)(menc + 8192);   // 8192
    float* rowsum  = zsum + 8192;             // 8192
    float* bnsum   = rowsum + 8192;           // 256
    float* bnsq    = bnsum + 256;             // 256
    float* scale   = bnsq + 256;              // 256
    float* shift   = scale + 256;             // 256

    auto encode_pass = [&](const float* x, float* h2_out) {
        hipMemsetAsync(menc, 0, 8192 * 4, stream);
        hipMemsetAsync(zsum, 0, 8192 * 4, stream);
        hipMemsetAsync(gat_buf, 0, (size_t)2097152 * 4, stream);
        hipMemsetAsync(h_buf, 0, (size_t)2097152 * 4, stream);
        // h = x @ W1  (split-K=2, atomic)
        sgemm_v2<<<dim3(4, 128, 2), 256, 0, stream>>>(x, W1, nullptr, h_buf,
                                                      NN, HID, IN, 1504, 1);
        attn_coeff<<<2048, 256, 0, stream>>>(h_buf, att_src, att_dst, asrc, adst);
        edge_logits<<<EE / 256, 256, 0, stream>>>(src, dst, asrc, adst, ebuf, menc);
        edge_softmax<<<EE / 256, 256, 0, stream>>>(dst, ebuf, menc, zsum);
        edge_aggregate<<<EE / 4, 256, 0, stream>>>(src, dst, ebuf, zsum, h_buf, gat_buf);
        elu_inplace<<<2048, 256, 0, stream>>>(gat_buf, (long)NN * HID);
        // h2 = h1 @ W2  (split-K=4, atomic)
        hipMemsetAsync(h2_out, 0, (size_t)524288 * 4, stream);
        sgemm_v2<<<dim3(1, 128, 4), 256, 0, stream>>>(gat_buf, W2, nullptr, h2_out,
                                                      NN, OUT, HID, 64, 1);
    };

    encode_pass(feat, h2);
    encode_pass(feat_a, h2a);

    // ---- decoder: h3 = elu(BN(h2 @ Wd1 + bd1)) @ Wd2 + bd2
    sgemm_v2<<<dim3(4, 128, 1), 256, 0, stream>>>(h2, Wd1, bd1, zdec,
                                                  NN, HID, OUT, OUT, 0);
    hipMemsetAsync(bnsum, 0, 512 * 4, stream);  // bnsum + bnsq contiguous
    bn_partial<<<64, 256, 0, stream>>>(zdec, bnsum, bnsq);
    bn_finalize<<<1, 256, 0, stream>>>(bnsum, bnsq, gamma, beta, scale, shift);
    bn_apply_elu<<<2048, 256, 0, stream>>>(zdec, scale, shift);
    sgemm_v2<<<dim3(47, 128, 1), 256, 0, stream>>>(zdec, Wd2, bd2, out + O_H3,
                                                   NN, IN, HID, HID, 0);

    // ---- readout (both graphs share graph_neigh; one GEMM with concat [h2|h2a])
    float* Hcat = zdec;                 // reuse (zdec free after Wd2 GEMM)
    float* vsum = zdec + 1048576;
    pack_hcat<<<4096, 256, 0, stream>>>(h2, h2a, Hcat);
    hipMemsetAsync(vsum, 0, (size_t)1048576 * 4, stream);
    hipMemsetAsync(rowsum, 0, 8192 * 4, stream);
    readout_gemm<<<dim3(64, 8), 256, 0, stream>>>(gneigh, Hcat, vsum, rowsum);
    readout_norm<<<8192, 128, 0, stream>>>(vsum, rowsum, gbuf, gabuf);

    // ---- discriminator
    disc_kernel<<<8192, 128, 0, stream>>>(h2, h2a, gbuf, gabuf, disc_W, disc_b,
                                          out + O_RET, out + O_RETA);

    // ---- copy h2 outputs (slots 0, 4, 5)
    copy_h2<<<2048, 256, 0, stream>>>(h2, h2a, out);
}

// Round 4
// 1239.052 us; speedup vs baseline: 3.5685x; 2.3931x over previous
//
#include <hip/hip_runtime.h>
#include <hip/hip_bf16.h>
#include <math.h>

// Problem dims
constexpr int NN  = 8192;
constexpr int EE  = 262144;
constexpr int IN  = 3000;
constexpr int HID = 256;
constexpr int OUT = 64;

// Output offsets (floats) in d_out: (h2, h3, ret, ret_a, h2, h2_a)
constexpr long O_H2   = 0;
constexpr long O_H3   = 524288;          // 8192*64
constexpr long O_RET  = 25100288;        // + 8192*3000
constexpr long O_RETA = 25116672;        // + 8192*2
constexpr long O_H2B  = 25133056;        // + 8192*2
constexpr long O_H2A  = 25657344;        // + 8192*64

// ---------------- sgemm_v2: C[M,N] = A[M,K]@B[K,N] (+bias) --------------------------------
__global__ __launch_bounds__(256) void sgemm_v2(const float* __restrict__ A,
                                                const float* __restrict__ B,
                                                const float* __restrict__ bias,
                                                float* __restrict__ C,
                                                int M, int N, int K,
                                                int kchunk, int atomic_out) {
    __shared__ float As[32][68];   // [k][row]
    __shared__ float Bs[32][68];   // [k][col]
    int t = threadIdx.x;
    int row0 = blockIdx.y * 64;
    int col0 = blockIdx.x * 64;
    int kbeg = blockIdx.z * kchunk;
    int kend = min(K, kbeg + kchunk);

    int ar  = t & 63;            // A row within tile
    int akq = (t >> 6) * 8;      // A k-offset (wave id * 8)
    int bkr = t >> 3;            // B k-row 0..31
    int bcq = (t & 7) * 8;       // B col-offset
    const float* Arow = A + (long)(row0 + ar) * K;
    int tx4 = (t & 15) * 4, ty4 = (t >> 4) * 4;

    float acc[4][4] = {};
    for (int k0 = kbeg; k0 < kend; k0 += 32) {
        if (k0 + 32 <= kend) {
            float4 v0 = *reinterpret_cast<const float4*>(Arow + k0 + akq);
            float4 v1 = *reinterpret_cast<const float4*>(Arow + k0 + akq + 4);
            As[akq+0][ar]=v0.x; As[akq+1][ar]=v0.y; As[akq+2][ar]=v0.z; As[akq+3][ar]=v0.w;
            As[akq+4][ar]=v1.x; As[akq+5][ar]=v1.y; As[akq+6][ar]=v1.z; As[akq+7][ar]=v1.w;
        } else {
#pragma unroll
            for (int i = 0; i < 8; ++i) {
                int gk = k0 + akq + i;
                As[akq+i][ar] = (gk < kend) ? Arow[gk] : 0.f;
            }
        }
        {
            int gk = k0 + bkr;
            int gc = col0 + bcq;
            if (gk < kend && gc + 8 <= N) {
                const float* Bp = B + (long)gk * N + gc;
                *reinterpret_cast<float4*>(&Bs[bkr][bcq])   = *reinterpret_cast<const float4*>(Bp);
                *reinterpret_cast<float4*>(&Bs[bkr][bcq+4]) = *reinterpret_cast<const float4*>(Bp + 4);
            } else {
#pragma unroll
                for (int i = 0; i < 8; ++i) {
                    int c = gc + i;
                    Bs[bkr][bcq+i] = (gk < kend && c < N) ? B[(long)gk * N + c] : 0.f;
                }
            }
        }
        __syncthreads();
#pragma unroll
        for (int k = 0; k < 32; ++k) {
            float4 a = *reinterpret_cast<const float4*>(&As[k][ty4]);
            float4 b = *reinterpret_cast<const float4*>(&Bs[k][tx4]);
            float av[4] = {a.x, a.y, a.z, a.w};
            float bv[4] = {b.x, b.y, b.z, b.w};
#pragma unroll
            for (int i = 0; i < 4; ++i)
#pragma unroll
                for (int j = 0; j < 4; ++j) acc[i][j] += av[i] * bv[j];
        }
        __syncthreads();
    }
#pragma unroll
    for (int i = 0; i < 4; ++i) {
        int gr = row0 + ty4 + i;
#pragma unroll
        for (int j = 0; j < 4; ++j) {
            int gc = col0 + tx4 + j;
            if (gc < N) {
                long idx = (long)gr * N + gc;
                if (atomic_out) atomicAdd(&C[idx], acc[i][j]);
                else            C[idx] = acc[i][j] + (bias ? bias[gc] : 0.f);
            }
        }
    }
}

// ---------------- readout GEMM: vsum[8192,128] = gn[8192,8192] @ Hcat[8192,128] -----------
__global__ __launch_bounds__(256) void readout_gemm(const float* __restrict__ gn,
                                                    const float* __restrict__ Hc,
                                                    float* __restrict__ vsum,
                                                    float* __restrict__ rowsum) {
    __shared__ float As[32][132];  // [k][row 0..127]
    __shared__ float Bs[32][132];  // [k][col 0..127]
    __shared__ float rs[2][128];
    int t = threadIdx.x;
    int row0 = blockIdx.x * 128;
    int kbeg = blockIdx.y * 1024;

    int ar  = t & 127;            // A row
    int akq = (t >> 7) * 16;      // 0 or 16
    const float* Arow = gn + (long)(row0 + ar) * NN;
    int bkr = t >> 3;             // 0..31
    int bcq = (t & 7) * 16;       // 0..112
    int tx8 = (t & 15) * 8, ty8 = (t >> 4) * 8;

    float acc[8][8] = {};
    float myrs = 0.f;
    for (int k0 = kbeg; k0 < kbeg + 1024; k0 += 32) {
#pragma unroll
        for (int q = 0; q < 4; ++q) {
            float4 v = *reinterpret_cast<const float4*>(Arow + k0 + akq + q * 4);
            As[akq + q*4 + 0][ar] = v.x;
            As[akq + q*4 + 1][ar] = v.y;
            As[akq + q*4 + 2][ar] = v.z;
            As[akq + q*4 + 3][ar] = v.w;
            myrs += v.x + v.y + v.z + v.w;
        }
        {
            const float* Bp = Hc + (long)(k0 + bkr) * 128 + bcq;
#pragma unroll
            for (int q = 0; q < 4; ++q)
                *reinterpret_cast<float4*>(&Bs[bkr][bcq + q*4]) =
                    *reinterpret_cast<const float4*>(Bp + q*4);
        }
        __syncthreads();
#pragma unroll
        for (int k = 0; k < 32; ++k) {
            float4 a0 = *reinterpret_cast<const float4*>(&As[k][ty8]);
            float4 a1 = *reinterpret_cast<const float4*>(&As[k][ty8 + 4]);
            float4 b0 = *reinterpret_cast<const float4*>(&Bs[k][tx8]);
            float4 b1 = *reinterpret_cast<const float4*>(&Bs[k][tx8 + 4]);
            float av[8] = {a0.x,a0.y,a0.z,a0.w,a1.x,a1.y,a1.z,a1.w};
            float bv[8] = {b0.x,b0.y,b0.z,b0.w,b1.x,b1.y,b1.z,b1.w};
#pragma unroll
            for (int i = 0; i < 8; ++i)
#pragma unroll
                for (int j = 0; j < 8; ++j) acc[i][j] += av[i] * bv[j];
        }
        __syncthreads();
    }
    rs[t >> 7][ar] = myrs;
    __syncthreads();
    if (t < 128) atomicAdd(&rowsum[row0 + t], rs[0][t] + rs[1][t]);
#pragma unroll
    for (int i = 0; i < 8; ++i) {
        long base = (long)(row0 + ty8 + i) * 128;
#pragma unroll
        for (int j = 0; j < 8; ++j)
            atomicAdd(&vsum[base + tx8 + j], acc[i][j]);
    }
}

// ---------------- CSR build (once per launch; edges shared by both passes) -----------------
__global__ void deg_count(const int* __restrict__ dst, int* __restrict__ deg) {
    int i = blockIdx.x * 256 + threadIdx.x;
    if (i < EE) atomicAdd(&deg[dst[i]], 1);
}

__global__ __launch_bounds__(256) void scan_offsets(const int* __restrict__ deg,
                                                    int* __restrict__ off,
                                                    int* __restrict__ cursor) {
    __shared__ int part[256];
    int t = threadIdx.x;
    int base = t * 32;
    int local[32];
    int s = 0;
#pragma unroll
    for (int i = 0; i < 32; ++i) { local[i] = s; s += deg[base + i]; }
    part[t] = s;
    __syncthreads();
    for (int o2 = 1; o2 < 256; o2 <<= 1) {
        int v = (t >= o2) ? part[t - o2] : 0;
        __syncthreads();
        part[t] += v;
        __syncthreads();
    }
    int pre = (t == 0) ? 0 : part[t - 1];
#pragma unroll
    for (int i = 0; i < 32; ++i) {
        int v = pre + local[i];
        off[base + i] = v;
        cursor[base + i] = v;
    }
}

__global__ void scatter_edges(const int* __restrict__ src, const int* __restrict__ dst,
                              int* __restrict__ cursor, int* __restrict__ ssrc) {
    int i = blockIdx.x * 256 + threadIdx.x;
    if (i >= EE) return;
    int slot = atomicAdd(&cursor[dst[i]], 1);
    ssrc[slot] = src[i];
}

// ---------------- attention coefficients ---------------------------------------------------
__global__ void attn_coeff(const float* __restrict__ h, const float* __restrict__ att_src,
                           const float* __restrict__ att_dst, float* __restrict__ a_src,
                           float* __restrict__ a_dst) {
    int wave = threadIdx.x >> 6;
    int lane = threadIdx.x & 63;
    int n = blockIdx.x * 4 + wave;
    float s1 = 0.f, s2 = 0.f;
#pragma unroll
    for (int c = 0; c < 4; ++c) {
        int j = c * 64 + lane;
        float hv = h[(long)n * HID + j];
        s1 += hv * att_src[j];
        s2 += hv * att_dst[j];
    }
    for (int off = 32; off > 0; off >>= 1) {
        s1 += __shfl_down(s1, off);
        s2 += __shfl_down(s2, off);
    }
    if (lane == 0) { a_src[n] = s1; a_dst[n] = s2; }
}

// ---------------- fused GAT gather: segment softmax + aggregation + ELU --------------------
// One wave per dst node. Phase A: segment max & sum (lane-parallel over in-edges).
// Phase B: serial edge loop, each lane owns 4 channels (float4), non-atomic write.
__global__ __launch_bounds__(256) void gat_gather(const int* __restrict__ ssrc,
                                                  const int* __restrict__ off,
                                                  const int* __restrict__ deg,
                                                  const float* __restrict__ asrc,
                                                  const float* __restrict__ adst,
                                                  const float* __restrict__ h,
                                                  float* __restrict__ gat) {
    int wv = threadIdx.x >> 6, lane = threadIdx.x & 63;
    int d = blockIdx.x * 4 + wv;
    int o = off[d], n = deg[d];
    float ad = adst[d];

    // phase A1: segment max
    float m = -INFINITY;
    for (int j = lane; j < n; j += 64) {
        float e = asrc[ssrc[o + j]] + ad;
        e = e > 0.f ? e : 0.2f * e;
        m = fmaxf(m, e);
    }
#pragma unroll
    for (int t = 32; t; t >>= 1) m = fmaxf(m, __shfl_xor(m, t));
    // phase A2: segment sum of exp
    float z = 0.f;
    for (int j = lane; j < n; j += 64) {
        float e = asrc[ssrc[o + j]] + ad;
        e = e > 0.f ? e : 0.2f * e;
        z += expf(e - m);
    }
#pragma unroll
    for (int t = 32; t; t >>= 1) z += __shfl_xor(z, t);
    float zinv = 1.0f / (z + 1e-16f);

    // phase B: weighted gather (2-way unrolled)
    float4 acc = {0.f, 0.f, 0.f, 0.f};
    int j = 0;
    for (; j + 2 <= n; j += 2) {
        int s0 = ssrc[o + j], s1 = ssrc[o + j + 1];
        const float4 h0 = *reinterpret_cast<const float4*>(&h[(long)s0 * HID + lane * 4]);
        const float4 h1 = *reinterpret_cast<const float4*>(&h[(long)s1 * HID + lane * 4]);
        float e0 = asrc[s0] + ad; e0 = e0 > 0.f ? e0 : 0.2f * e0;
        float e1 = asrc[s1] + ad; e1 = e1 > 0.f ? e1 : 0.2f * e1;
        float a0 = expf(e0 - m) * zinv;
        float a1 = expf(e1 - m) * zinv;
        acc.x += a0 * h0.x + a1 * h1.x;
        acc.y += a0 * h0.y + a1 * h1.y;
        acc.z += a0 * h0.z + a1 * h1.z;
        acc.w += a0 * h0.w + a1 * h1.w;
    }
    if (j < n) {
        int s0 = ssrc[o + j];
        const float4 h0 = *reinterpret_cast<const float4*>(&h[(long)s0 * HID + lane * 4]);
        float e0 = asrc[s0] + ad; e0 = e0 > 0.f ? e0 : 0.2f * e0;
        float a0 = expf(e0 - m) * zinv;
        acc.x += a0 * h0.x; acc.y += a0 * h0.y; acc.z += a0 * h0.z; acc.w += a0 * h0.w;
    }
    // fused ELU + write
    float4 r;
    r.x = acc.x > 0.f ? acc.x : expm1f(acc.x);
    r.y = acc.y > 0.f ? acc.y : expm1f(acc.y);
    r.z = acc.z > 0.f ? acc.z : expm1f(acc.z);
    r.w = acc.w > 0.f ? acc.w : expm1f(acc.w);
    *reinterpret_cast<float4*>(&gat[(long)d * HID + lane * 4]) = r;
}

// ---------------- batchnorm ----------------------------------------------------------------
__global__ void bn_partial(const float* __restrict__ zd, float* __restrict__ s,
                           float* __restrict__ sq) {
    int t = threadIdx.x;  // column
    float a = 0.f, b = 0.f;
    int r0 = blockIdx.x * 128;
    for (int r = r0; r < r0 + 128; ++r) {
        float v = zd[(long)r * HID + t];
        a += v;
        b += v * v;
    }
    atomicAdd(&s[t], a);
    atomicAdd(&sq[t], b);
}

__global__ void bn_finalize(const float* __restrict__ s, const float* __restrict__ sq,
                            const float* __restrict__ gamma, const float* __restrict__ beta,
                            float* __restrict__ scale, float* __restrict__ shift) {
    int t = threadIdx.x;
    float mean = s[t] / (float)NN;
    float var  = sq[t] / (float)NN - mean * mean;
    float sc   = gamma[t] * rsqrtf(var + 1e-5f);
    scale[t] = sc;
    shift[t] = beta[t] - mean * sc;
}

__global__ void bn_apply_elu(float* __restrict__ zd, const float* __restrict__ scale,
                             const float* __restrict__ shift) {
    for (long i = (long)blockIdx.x * blockDim.x + threadIdx.x; i < (long)NN * HID;
         i += (long)gridDim.x * blockDim.x) {
        int c = (int)(i & 255);
        float v = zd[i] * scale[c] + shift[c];
        zd[i] = v > 0.f ? v : expm1f(v);
    }
}

// ---------------- readout tail -------------------------------------------------------------
__global__ void pack_hcat(const float* __restrict__ h2, const float* __restrict__ h2a,
                          float* __restrict__ Hcat) {
    int i = blockIdx.x * 256 + threadIdx.x;   // 8192*128 total
    int r = i >> 7, c = i & 127;
    Hcat[i] = (c < 64) ? h2[(long)r * 64 + c] : h2a[(long)r * 64 + (c - 64)];
}

__global__ void readout_norm(const float* __restrict__ vsum, const float* __restrict__ rowsum,
                             float* __restrict__ g, float* __restrict__ ga) {
    int r = blockIdx.x;
    int w = threadIdx.x >> 6, lane = threadIdx.x & 63;
    float v = vsum[(long)r * 128 + w * 64 + lane] / rowsum[r];
    float sq = v * v;
    for (int off = 32; off > 0; off >>= 1) sq += __shfl_xor(sq, off);
    float nrm = fmaxf(sqrtf(sq), 1e-12f);
    float out = 1.0f / (1.0f + expf(-(v / nrm)));
    (w == 0 ? g : ga)[(long)r * 64 + lane] = out;
}

// ---------------- discriminator ------------------------------------------------------------
__global__ void disc_kernel(const float* __restrict__ h2, const float* __restrict__ h2a,
                            const float* __restrict__ g, const float* __restrict__ ga,
                            const float* __restrict__ W, const float* __restrict__ b,
                            float* __restrict__ ret, float* __restrict__ reta) {
    int n = blockIdx.x;
    int w = threadIdx.x >> 6, lane = threadIdx.x & 63;  // lane = d
    const float* c = (w == 0) ? g : ga;
    float u = 0.f;
#pragma unroll 8
    for (int e = 0; e < 64; ++e) u += W[lane * 64 + e] * c[(long)n * 64 + e];
    float hp = ((w == 0) ? h2 : h2a)[(long)n * 64 + lane];
    float hm = ((w == 0) ? h2a : h2)[(long)n * 64 + lane];
    float t1 = hp * u, t2 = hm * u;
    for (int off = 32; off > 0; off >>= 1) {
        t1 += __shfl_xor(t1, off);
        t2 += __shfl_xor(t2, off);
    }
    if (lane == 0) {
        float bb = b[0];
        if (w == 0) { ret[n * 2] = t1 + bb;  ret[n * 2 + 1] = t2 + bb; }
        else        { reta[n * 2] = t1 + bb; reta[n * 2 + 1] = t2 + bb; }
    }
}

__global__ void copy_h2(const float* __restrict__ h2, const float* __restrict__ h2a,
                        float* __restrict__ out) {
    int i = blockIdx.x * 256 + threadIdx.x;   // 524288 total
    float v = h2[i], va = h2a[i];
    out[O_H2 + i]  = v;
    out[O_H2B + i] = v;
    out[O_H2A + i] = va;
}

// ---------------- driver -------------------------------------------------------------------
extern "C" void kernel_launch(void* const* d_in, const int* in_sizes, int n_in,
                              void* d_out, int out_size, void* d_ws, size_t ws_size,
                              hipStream_t stream) {
    const float* feat    = (const float*)d_in[0];
    const float* feat_a  = (const float*)d_in[1];
    const float* gneigh  = (const float*)d_in[2];
    const float* W1      = (const float*)d_in[3];
    const float* att_src = (const float*)d_in[4];
    const float* att_dst = (const float*)d_in[5];
    const float* W2      = (const float*)d_in[6];
    const float* Wd1     = (const float*)d_in[7];
    const float* bd1     = (const float*)d_in[8];
    const float* gamma   = (const float*)d_in[9];
    const float* beta    = (const float*)d_in[10];
    const float* Wd2     = (const float*)d_in[11];
    const float* bd2     = (const float*)d_in[12];
    const float* disc_W  = (const float*)d_in[13];
    const float* disc_b  = (const float*)d_in[14];
    const int*   eidx    = (const int*)d_in[15];
    const int*   src = eidx;
    const int*   dst = eidx + EE;
    float* out = (float*)d_out;

    // workspace layout (floats)
    float* w = (float*)d_ws;
    float* h_buf   = w;                       // 2097152
    float* gat_buf = h_buf + 2097152;         // 2097152
    float* zdec    = gat_buf + 2097152;       // 2097152 (later reused: Hcat | vsum)
    float* h2      = zdec + 2097152;          // 524288
    float* h2a     = h2 + 524288;             // 524288
    float* gbuf    = h2a + 524288;            // 524288
    float* gabuf   = gbuf + 524288;           // 524288
    float* asrc    = gabuf + 524288;          // 8192
    float* adst    = asrc + 8192;             // 8192
    float* rowsum  = adst + 8192;             // 8192
    float* bnsum   = rowsum + 8192;           // 256
    float* bnsq    = bnsum + 256;             // 256
    float* scale   = bnsq + 256;              // 256
    float* shift   = scale + 256;             // 256
    int*   ideg    = (int*)(shift + 256);     // 8192
    int*   ioff    = ideg + 8192;             // 8192
    int*   icur    = ioff + 8192;             // 8192
    int*   issrc   = icur + 8192;             // 262144

    // ---- CSR build (edge_index is shared by both encode passes)
    hipMemsetAsync(ideg, 0, 8192 * 4, stream);
    deg_count<<<EE / 256, 256, 0, stream>>>(dst, ideg);
    scan_offsets<<<1, 256, 0, stream>>>(ideg, ioff, icur);
    scatter_edges<<<EE / 256, 256, 0, stream>>>(src, dst, icur, issrc);

    auto encode_pass = [&](const float* x, float* h2_out) {
        hipMemsetAsync(h_buf, 0, (size_t)2097152 * 4, stream);
        // h = x @ W1  (split-K=2, atomic)
        sgemm_v2<<<dim3(4, 128, 2), 256, 0, stream>>>(x, W1, nullptr, h_buf,
                                                      NN, HID, IN, 1504, 1);
        attn_coeff<<<2048, 256, 0, stream>>>(h_buf, att_src, att_dst, asrc, adst);
        // fused segment-softmax + gather aggregation + ELU
        gat_gather<<<2048, 256, 0, stream>>>(issrc, ioff, ideg, asrc, adst, h_buf, gat_buf);
        // h2 = h1 @ W2  (split-K=4, atomic)
        hipMemsetAsync(h2_out, 0, (size_t)524288 * 4, stream);
        sgemm_v2<<<dim3(1, 128, 4), 256, 0, stream>>>(gat_buf, W2, nullptr, h2_out,
                                                      NN, OUT, HID, 64, 1);
    };

    encode_pass(feat, h2);
    encode_pass(feat_a, h2a);

    // ---- decoder: h3 = elu(BN(h2 @ Wd1 + bd1)) @ Wd2 + bd2
    sgemm_v2<<<dim3(4, 128, 1), 256, 0, stream>>>(h2, Wd1, bd1, zdec,
                                                  NN, HID, OUT, OUT, 0);
    hipMemsetAsync(bnsum, 0, 512 * 4, stream);  // bnsum + bnsq contiguous
    bn_partial<<<64, 256, 0, stream>>>(zdec, bnsum, bnsq);
    bn_finalize<<<1, 256, 0, stream>>>(bnsum, bnsq, gamma, beta, scale, shift);
    bn_apply_elu<<<2048, 256, 0, stream>>>(zdec, scale, shift);
    sgemm_v2<<<dim3(47, 128, 1), 256, 0, stream>>>(zdec, Wd2, bd2, out + O_H3,
                                                   NN, IN, HID, HID, 0);

    // ---- readout (both graphs share graph_neigh; one GEMM with concat [h2|h2a])
    float* Hcat = zdec;                 // reuse (zdec free after Wd2 GEMM)
    float* vsum = zdec + 1048576;
    pack_hcat<<<4096, 256, 0, stream>>>(h2, h2a, Hcat);
    hipMemsetAsync(vsum, 0, (size_t)1048576 * 4, stream);
    hipMemsetAsync(rowsum, 0, 8192 * 4, stream);
    readout_gemm<<<dim3(64, 8), 256, 0, stream>>>(gneigh, Hcat, vsum, rowsum);
    readout_norm<<<8192, 128, 0, stream>>>(vsum, rowsum, gbuf, gabuf);

    // ---- discriminator
    disc_kernel<<<8192, 128, 0, stream>>>(h2, h2a, gbuf, gabuf, disc_W, disc_b,
                                          out + O_RET, out + O_RETA);

    // ---- copy h2 outputs (slots 0, 4, 5)
    copy_h2<<<2048, 256, 0, stream>>>(h2, h2a, out);
}

// Round 6
// 712.796 us; speedup vs baseline: 6.2031x; 1.7383x over previous
//
#include <hip/hip_runtime.h>
#include <hip/hip_bf16.h>
#include <math.h>

// Problem dims
constexpr int NN  = 8192;
constexpr int EE  = 262144;
constexpr int IN  = 3000;
constexpr int HID = 256;
constexpr int OUT = 64;

// Output offsets (floats) in d_out: (h2, h3, ret, ret_a, h2, h2_a)
constexpr long O_H2   = 0;
constexpr long O_H3   = 524288;          // 8192*64
constexpr long O_RET  = 25100288;        // + 8192*3000
constexpr long O_RETA = 25116672;        // + 8192*2
constexpr long O_H2B  = 25133056;        // + 8192*2
constexpr long O_H2A  = 25657344;        // + 8192*64

typedef __attribute__((ext_vector_type(8))) short short8v;   // 8 bf16 (4 VGPRs)
typedef __attribute__((ext_vector_type(4))) float f32x4;     // MFMA accumulator

__device__ __forceinline__ short f2bf(float f) {   // RNE f32 -> bf16 bits
    unsigned u = __float_as_uint(f);
    return (short)((u + 0x7FFF + ((u >> 16) & 1)) >> 16);
}

// ---------------- bf16 MFMA GEMM: C[M,N] = A[M,K]@B[K,N] (+bias) --------------------------
// BM=64,BN=64,BK=32, 256 thr (4 waves, 2x2 wave grid, 32x32 per wave = 4 MFMA tiles).
// A,B are f32 in global; converted to bf16 during LDS staging. M must be mult of 64.
// Fragment layouts (gfx950 16x16x32): A: row=l&15, k=(l>>4)*8+j ; B: col=l&15, same k;
// D: col=l&15, row=(l>>4)*4+q  [m89-verified].
__global__ __launch_bounds__(256) void mfma_gemm(const float* __restrict__ A,
                                                 const float* __restrict__ B,
                                                 const float* __restrict__ bias,
                                                 float* __restrict__ C,
                                                 int M, int N, int K) {
    __shared__ short As[64][40];   // [row][k], pad 40 (80B rows, 16B-aligned)
    __shared__ short Bs[64][40];   // [col][k]
    int t = threadIdx.x;
    int w = t >> 6, l = t & 63;
    int row0 = blockIdx.y * 64, col0 = blockIdx.x * 64;
    int sr = t & 63;               // staging row (A) / col (B)
    int sk = (t >> 6) * 8;         // staging k offset
    int wm = (w >> 1) * 32, wn = (w & 1) * 32;
    int fr = l & 15, fk = (l >> 4) * 8;
    const float* Arow = A + (long)(row0 + sr) * K;

    f32x4 acc[2][2] = {};
    for (int k0 = 0; k0 < K; k0 += 32) {
        short8v av;
        if (k0 + 32 <= K) {
            float4 v0 = *reinterpret_cast<const float4*>(Arow + k0 + sk);
            float4 v1 = *reinterpret_cast<const float4*>(Arow + k0 + sk + 4);
            av[0]=f2bf(v0.x); av[1]=f2bf(v0.y); av[2]=f2bf(v0.z); av[3]=f2bf(v0.w);
            av[4]=f2bf(v1.x); av[5]=f2bf(v1.y); av[6]=f2bf(v1.z); av[7]=f2bf(v1.w);
        } else {
#pragma unroll
            for (int i = 0; i < 8; ++i) {
                int gk = k0 + sk + i;
                av[i] = f2bf(gk < K ? Arow[gk] : 0.f);
            }
        }
        *reinterpret_cast<short8v*>(&As[sr][sk]) = av;
        {
            short8v bv;
            int gc = col0 + sr;
            bool cok = gc < N;
#pragma unroll
            for (int i = 0; i < 8; ++i) {
                int gk = k0 + sk + i;
                bv[i] = f2bf((cok && gk < K) ? B[(long)gk * N + gc] : 0.f);
            }
            *reinterpret_cast<short8v*>(&Bs[sr][sk]) = bv;
        }
        __syncthreads();
        short8v a0 = *reinterpret_cast<short8v*>(&As[wm + fr][fk]);
        short8v a1 = *reinterpret_cast<short8v*>(&As[wm + 16 + fr][fk]);
        short8v b0 = *reinterpret_cast<short8v*>(&Bs[wn + fr][fk]);
        short8v b1 = *reinterpret_cast<short8v*>(&Bs[wn + 16 + fr][fk]);
        acc[0][0] = __builtin_amdgcn_mfma_f32_16x16x32_bf16(a0, b0, acc[0][0], 0, 0, 0);
        acc[0][1] = __builtin_amdgcn_mfma_f32_16x16x32_bf16(a0, b1, acc[0][1], 0, 0, 0);
        acc[1][0] = __builtin_amdgcn_mfma_f32_16x16x32_bf16(a1, b0, acc[1][0], 0, 0, 0);
        acc[1][1] = __builtin_amdgcn_mfma_f32_16x16x32_bf16(a1, b1, acc[1][1], 0, 0, 0);
        __syncthreads();
    }
    int dr = (l >> 4) * 4, dc = l & 15;
#pragma unroll
    for (int i = 0; i < 2; ++i)
#pragma unroll
        for (int j = 0; j < 2; ++j) {
            int c = col0 + wn + j * 16 + dc;
            if (c < N) {
                float bb = bias ? bias[c] : 0.f;
#pragma unroll
                for (int q = 0; q < 4; ++q) {
                    int r = row0 + wm + i * 16 + dr + q;
                    C[(long)r * N + c] = acc[i][j][q] + bb;
                }
            }
        }
}

// ---------------- readout MFMA: vsum[8192,128] = gneigh @ Hcat_bf, fused rowsum ------------
// BM=64, BN=128, BK=32, split-K=4 (kchunk 2048). Non-atomic: per-chunk partial buffers.
// grid (128 row-tiles, 4 k-chunks).
__global__ __launch_bounds__(256) void readout_mfma(const float* __restrict__ gn,
                                                    const unsigned short* __restrict__ Hb,
                                                    float* __restrict__ vsum_part,
                                                    float* __restrict__ rowsum_part) {
    __shared__ short As[64][40];     // [row][k]
    __shared__ short Bs[128][40];    // [col][k]
    __shared__ float rsacc[64][4];
    int t = threadIdx.x;
    int w = t >> 6, l = t & 63;
    int row0 = blockIdx.x * 64;
    int kc   = blockIdx.y;
    int kbeg = kc * 2048;
    int sr = t & 63;
    int sk = (t >> 6) * 8;
    int wm = (w >> 1) * 32, wn = (w & 1) * 64;
    int fr = l & 15, fk = (l >> 4) * 8;
    const float* Arow = gn + (long)(row0 + sr) * NN;

    f32x4 acc[2][4] = {};
    float myrs = 0.f;
    for (int k0 = kbeg; k0 < kbeg + 2048; k0 += 32) {
        {
            float4 v0 = *reinterpret_cast<const float4*>(Arow + k0 + sk);
            float4 v1 = *reinterpret_cast<const float4*>(Arow + k0 + sk + 4);
            short8v av;
            av[0]=f2bf(v0.x); av[1]=f2bf(v0.y); av[2]=f2bf(v0.z); av[3]=f2bf(v0.w);
            av[4]=f2bf(v1.x); av[5]=f2bf(v1.y); av[6]=f2bf(v1.z); av[7]=f2bf(v1.w);
            myrs += v0.x + v0.y + v0.z + v0.w + v1.x + v1.y + v1.z + v1.w;
            *reinterpret_cast<short8v*>(&As[sr][sk]) = av;
        }
#pragma unroll
        for (int cc = 0; cc < 2; ++cc) {
            int col = cc * 64 + sr;
            short8v bv;
#pragma unroll
            for (int i = 0; i < 8; ++i)
                bv[i] = (short)Hb[(long)(k0 + sk + i) * 128 + col];
            *reinterpret_cast<short8v*>(&Bs[col][sk]) = bv;
        }
        __syncthreads();
        short8v a0 = *reinterpret_cast<short8v*>(&As[wm + fr][fk]);
        short8v a1 = *reinterpret_cast<short8v*>(&As[wm + 16 + fr][fk]);
#pragma unroll
        for (int j = 0; j < 4; ++j) {
            short8v bf = *reinterpret_cast<short8v*>(&Bs[wn + j * 16 + fr][fk]);
            acc[0][j] = __builtin_amdgcn_mfma_f32_16x16x32_bf16(a0, bf, acc[0][j], 0, 0, 0);
            acc[1][j] = __builtin_amdgcn_mfma_f32_16x16x32_bf16(a1, bf, acc[1][j], 0, 0, 0);
        }
        __syncthreads();
    }
    // fused rowsum (exact, from f32 staged values)
    rsacc[sr][t >> 6] = myrs;
    __syncthreads();
    if (t < 64)
        rowsum_part[(long)kc * NN + row0 + t] =
            rsacc[t][0] + rsacc[t][1] + rsacc[t][2] + rsacc[t][3];
    int dr = (l >> 4) * 4, dc = l & 15;
#pragma unroll
    for (int i = 0; i < 2; ++i)
#pragma unroll
        for (int j = 0; j < 4; ++j) {
            int c = wn + j * 16 + dc;
#pragma unroll
            for (int q = 0; q < 4; ++q) {
                int r = row0 + wm + i * 16 + dr + q;
                vsum_part[((long)kc * NN + r) * 128 + c] = acc[i][j][q];
            }
        }
}

// ---------------- f32 SGEMM (kept for Wd1: small, feeds BN) -------------------------------
__global__ __launch_bounds__(256) void sgemm_v2(const float* __restrict__ A,
                                                const float* __restrict__ B,
                                                const float* __restrict__ bias,
                                                float* __restrict__ C,
                                                int M, int N, int K,
                                                int kchunk, int atomic_out) {
    __shared__ float As[32][68];
    __shared__ float Bs[32][68];
    int t = threadIdx.x;
    int row0 = blockIdx.y * 64;
    int col0 = blockIdx.x * 64;
    int kbeg = blockIdx.z * kchunk;
    int kend = min(K, kbeg + kchunk);
    int ar  = t & 63;
    int akq = (t >> 6) * 8;
    int bkr = t >> 3;
    int bcq = (t & 7) * 8;
    const float* Arow = A + (long)(row0 + ar) * K;
    int tx4 = (t & 15) * 4, ty4 = (t >> 4) * 4;

    float acc[4][4] = {};
    for (int k0 = kbeg; k0 < kend; k0 += 32) {
        if (k0 + 32 <= kend) {
            float4 v0 = *reinterpret_cast<const float4*>(Arow + k0 + akq);
            float4 v1 = *reinterpret_cast<const float4*>(Arow + k0 + akq + 4);
            As[akq+0][ar]=v0.x; As[akq+1][ar]=v0.y; As[akq+2][ar]=v0.z; As[akq+3][ar]=v0.w;
            As[akq+4][ar]=v1.x; As[akq+5][ar]=v1.y; As[akq+6][ar]=v1.z; As[akq+7][ar]=v1.w;
        } else {
#pragma unroll
            for (int i = 0; i < 8; ++i) {
                int gk = k0 + akq + i;
                As[akq+i][ar] = (gk < kend) ? Arow[gk] : 0.f;
            }
        }
        {
            int gk = k0 + bkr;
            int gc = col0 + bcq;
            if (gk < kend && gc + 8 <= N) {
                const float* Bp = B + (long)gk * N + gc;
                *reinterpret_cast<float4*>(&Bs[bkr][bcq])   = *reinterpret_cast<const float4*>(Bp);
                *reinterpret_cast<float4*>(&Bs[bkr][bcq+4]) = *reinterpret_cast<const float4*>(Bp + 4);
            } else {
#pragma unroll
                for (int i = 0; i < 8; ++i) {
                    int c = gc + i;
                    Bs[bkr][bcq+i] = (gk < kend && c < N) ? B[(long)gk * N + c] : 0.f;
                }
            }
        }
        __syncthreads();
#pragma unroll
        for (int k = 0; k < 32; ++k) {
            float4 a = *reinterpret_cast<const float4*>(&As[k][ty4]);
            float4 b = *reinterpret_cast<const float4*>(&Bs[k][tx4]);
            float av[4] = {a.x, a.y, a.z, a.w};
            float bv[4] = {b.x, b.y, b.z, b.w};
#pragma unroll
            for (int i = 0; i < 4; ++i)
#pragma unroll
                for (int j = 0; j < 4; ++j) acc[i][j] += av[i] * bv[j];
        }
        __syncthreads();
    }
#pragma unroll
    for (int i = 0; i < 4; ++i) {
        int gr = row0 + ty4 + i;
#pragma unroll
        for (int j = 0; j < 4; ++j) {
            int gc = col0 + tx4 + j;
            if (gc < N) {
                long idx = (long)gr * N + gc;
                if (atomic_out) atomicAdd(&C[idx], acc[i][j]);
                else            C[idx] = acc[i][j] + (bias ? bias[gc] : 0.f);
            }
        }
    }
}

// ---------------- CSR build ----------------------------------------------------------------
__global__ void deg_count(const int* __restrict__ dst, int* __restrict__ deg) {
    int i = blockIdx.x * 256 + threadIdx.x;
    if (i < EE) atomicAdd(&deg[dst[i]], 1);
}

__global__ __launch_bounds__(256) void scan_offsets(const int* __restrict__ deg,
                                                    int* __restrict__ off,
                                                    int* __restrict__ cursor) {
    __shared__ int part[256];
    int t = threadIdx.x;
    int base = t * 32;
    int local[32];
    int s = 0;
#pragma unroll
    for (int i = 0; i < 32; ++i) { local[i] = s; s += deg[base + i]; }
    part[t] = s;
    __syncthreads();
    for (int o2 = 1; o2 < 256; o2 <<= 1) {
        int v = (t >= o2) ? part[t - o2] : 0;
        __syncthreads();
        part[t] += v;
        __syncthreads();
    }
    int pre = (t == 0) ? 0 : part[t - 1];
#pragma unroll
    for (int i = 0; i < 32; ++i) {
        int v = pre + local[i];
        off[base + i] = v;
        cursor[base + i] = v;
    }
}

__global__ void scatter_edges(const int* __restrict__ src, const int* __restrict__ dst,
                              int* __restrict__ cursor, int* __restrict__ ssrc) {
    int i = blockIdx.x * 256 + threadIdx.x;
    if (i >= EE) return;
    int slot = atomicAdd(&cursor[dst[i]], 1);
    ssrc[slot] = src[i];
}

// ---------------- attention coefficients ---------------------------------------------------
__global__ void attn_coeff(const float* __restrict__ h, const float* __restrict__ att_src,
                           const float* __restrict__ att_dst, float* __restrict__ a_src,
                           float* __restrict__ a_dst) {
    int wave = threadIdx.x >> 6;
    int lane = threadIdx.x & 63;
    int n = blockIdx.x * 4 + wave;
    float s1 = 0.f, s2 = 0.f;
#pragma unroll
    for (int c = 0; c < 4; ++c) {
        int j = c * 64 + lane;
        float hv = h[(long)n * HID + j];
        s1 += hv * att_src[j];
        s2 += hv * att_dst[j];
    }
    for (int off = 32; off > 0; off >>= 1) {
        s1 += __shfl_down(s1, off);
        s2 += __shfl_down(s2, off);
    }
    if (lane == 0) { a_src[n] = s1; a_dst[n] = s2; }
}

// ---------------- fused GAT gather ---------------------------------------------------------
__global__ __launch_bounds__(256) void gat_gather(const int* __restrict__ ssrc,
                                                  const int* __restrict__ off,
                                                  const int* __restrict__ deg,
                                                  const float* __restrict__ asrc,
                                                  const float* __restrict__ adst,
                                                  const float* __restrict__ h,
                                                  float* __restrict__ gat) {
    int wv = threadIdx.x >> 6, lane = threadIdx.x & 63;
    int d = blockIdx.x * 4 + wv;
    int o = off[d], n = deg[d];
    float ad = adst[d];

    float m = -INFINITY;
    for (int j = lane; j < n; j += 64) {
        float e = asrc[ssrc[o + j]] + ad;
        e = e > 0.f ? e : 0.2f * e;
        m = fmaxf(m, e);
    }
#pragma unroll
    for (int t = 32; t; t >>= 1) m = fmaxf(m, __shfl_xor(m, t));
    float z = 0.f;
    for (int j = lane; j < n; j += 64) {
        float e = asrc[ssrc[o + j]] + ad;
        e = e > 0.f ? e : 0.2f * e;
        z += expf(e - m);
    }
#pragma unroll
    for (int t = 32; t; t >>= 1) z += __shfl_xor(z, t);
    float zinv = 1.0f / (z + 1e-16f);

    float4 acc = {0.f, 0.f, 0.f, 0.f};
    int j = 0;
    for (; j + 2 <= n; j += 2) {
        int s0 = ssrc[o + j], s1 = ssrc[o + j + 1];
        const float4 h0 = *reinterpret_cast<const float4*>(&h[(long)s0 * HID + lane * 4]);
        const float4 h1 = *reinterpret_cast<const float4*>(&h[(long)s1 * HID + lane * 4]);
        float e0 = asrc[s0] + ad; e0 = e0 > 0.f ? e0 : 0.2f * e0;
        float e1 = asrc[s1] + ad; e1 = e1 > 0.f ? e1 : 0.2f * e1;
        float a0 = expf(e0 - m) * zinv;
        float a1 = expf(e1 - m) * zinv;
        acc.x += a0 * h0.x + a1 * h1.x;
        acc.y += a0 * h0.y + a1 * h1.y;
        acc.z += a0 * h0.z + a1 * h1.z;
        acc.w += a0 * h0.w + a1 * h1.w;
    }
    if (j < n) {
        int s0 = ssrc[o + j];
        const float4 h0 = *reinterpret_cast<const float4*>(&h[(long)s0 * HID + lane * 4]);
        float e0 = asrc[s0] + ad; e0 = e0 > 0.f ? e0 : 0.2f * e0;
        float a0 = expf(e0 - m) * zinv;
        acc.x += a0 * h0.x; acc.y += a0 * h0.y; acc.z += a0 * h0.z; acc.w += a0 * h0.w;
    }
    float4 r;
    r.x = acc.x > 0.f ? acc.x : expm1f(acc.x);
    r.y = acc.y > 0.f ? acc.y : expm1f(acc.y);
    r.z = acc.z > 0.f ? acc.z : expm1f(acc.z);
    r.w = acc.w > 0.f ? acc.w : expm1f(acc.w);
    *reinterpret_cast<float4*>(&gat[(long)d * HID + lane * 4]) = r;
}

// ---------------- batchnorm ----------------------------------------------------------------
__global__ void bn_partial(const float* __restrict__ zd, float* __restrict__ s,
                           float* __restrict__ sq) {
    int t = threadIdx.x;
    float a = 0.f, b = 0.f;
    int r0 = blockIdx.x * 128;
    for (int r = r0; r < r0 + 128; ++r) {
        float v = zd[(long)r * HID + t];
        a += v;
        b += v * v;
    }
    atomicAdd(&s[t], a);
    atomicAdd(&sq[t], b);
}

__global__ void bn_finalize(const float* __restrict__ s, const float* __restrict__ sq,
                            const float* __restrict__ gamma, const float* __restrict__ beta,
                            float* __restrict__ scale, float* __restrict__ shift) {
    int t = threadIdx.x;
    float mean = s[t] / (float)NN;
    float var  = sq[t] / (float)NN - mean * mean;
    float sc   = gamma[t] * rsqrtf(var + 1e-5f);
    scale[t] = sc;
    shift[t] = beta[t] - mean * sc;
}

__global__ void bn_apply_elu(float* __restrict__ zd, const float* __restrict__ scale,
                             const float* __restrict__ shift) {
    for (long i = (long)blockIdx.x * blockDim.x + threadIdx.x; i < (long)NN * HID;
         i += (long)gridDim.x * blockDim.x) {
        int c = (int)(i & 255);
        float v = zd[i] * scale[c] + shift[c];
        zd[i] = v > 0.f ? v : expm1f(v);
    }
}

// ---------------- readout tail -------------------------------------------------------------
__global__ void pack_hcat_bf(const float* __restrict__ h2, const float* __restrict__ h2a,
                             unsigned short* __restrict__ Hb) {
    int i = blockIdx.x * 256 + threadIdx.x;   // 8192*128 total
    int r = i >> 7, c = i & 127;
    float v = (c < 64) ? h2[(long)r * 64 + c] : h2a[(long)r * 64 + (c - 64)];
    Hb[i] = (unsigned short)f2bf(v);
}

// block = row, 128 threads; sums the 4 split-K partials, then normalize + sigmoid.
__global__ void readout_norm2(const float* __restrict__ vsum_part,
                              const float* __restrict__ rowsum_part,
                              float* __restrict__ g, float* __restrict__ ga) {
    int r = blockIdx.x;
    int c = threadIdx.x;
    float v = 0.f;
#pragma unroll
    for (int kc = 0; kc < 4; ++kc)
        v += vsum_part[((long)kc * NN + r) * 128 + c];
    float rs = 0.f;
#pragma unroll
    for (int kc = 0; kc < 4; ++kc)
        rs += rowsum_part[(long)kc * NN + r];
    v /= rs;
    int w = c >> 6, lane = c & 63;
    float sq = v * v;
#pragma unroll
    for (int off = 32; off > 0; off >>= 1) sq += __shfl_xor(sq, off);
    float nrm = fmaxf(sqrtf(sq), 1e-12f);
    float out = 1.0f / (1.0f + expf(-(v / nrm)));
    (w == 0 ? g : ga)[(long)r * 64 + lane] = out;
}

// ---------------- discriminator ------------------------------------------------------------
__global__ void disc_kernel(const float* __restrict__ h2, const float* __restrict__ h2a,
                            const float* __restrict__ g, const float* __restrict__ ga,
                            const float* __restrict__ W, const float* __restrict__ b,
                            float* __restrict__ ret, float* __restrict__ reta) {
    int n = blockIdx.x;
    int w = threadIdx.x >> 6, lane = threadIdx.x & 63;
    const float* c = (w == 0) ? g : ga;
    float u = 0.f;
#pragma unroll 8
    for (int e = 0; e < 64; ++e) u += W[lane * 64 + e] * c[(long)n * 64 + e];
    float hp = ((w == 0) ? h2 : h2a)[(long)n * 64 + lane];
    float hm = ((w == 0) ? h2a : h2)[(long)n * 64 + lane];
    float t1 = hp * u, t2 = hm * u;
    for (int off = 32; off > 0; off >>= 1) {
        t1 += __shfl_xor(t1, off);
        t2 += __shfl_xor(t2, off);
    }
    if (lane == 0) {
        float bb = b[0];
        if (w == 0) { ret[n * 2] = t1 + bb;  ret[n * 2 + 1] = t2 + bb; }
        else        { reta[n * 2] = t1 + bb; reta[n * 2 + 1] = t2 + bb; }
    }
}

__global__ void copy_h2(const float* __restrict__ h2, const float* __restrict__ h2a,
                        float* __restrict__ out) {
    int i = blockIdx.x * 256 + threadIdx.x;
    float v = h2[i], va = h2a[i];
    out[O_H2 + i]  = v;
    out[O_H2B + i] = v;
    out[O_H2A + i] = va;
}

// ---------------- driver -------------------------------------------------------------------
extern "C" void kernel_launch(void* const* d_in, const int* in_sizes, int n_in,
                              void* d_out, int out_size, void* d_ws, size_t ws_size,
                              hipStream_t stream) {
    const float* feat    = (const float*)d_in[0];
    const float* feat_a  = (const float*)d_in[1];
    const float* gneigh  = (const float*)d_in[2];
    const float* W1      = (const float*)d_in[3];
    const float* att_src = (const float*)d_in[4];
    const float* att_dst = (const float*)d_in[5];
    const float* W2      = (const float*)d_in[6];
    const float* Wd1     = (const float*)d_in[7];
    const float* bd1     = (const float*)d_in[8];
    const float* gamma   = (const float*)d_in[9];
    const float* beta    = (const float*)d_in[10];
    const float* Wd2     = (const float*)d_in[11];
    const float* bd2     = (const float*)d_in[12];
    const float* disc_W  = (const float*)d_in[13];
    const float* disc_b  = (const float*)d_in[14];
    const int*   eidx    = (const int*)d_in[15];
    const int*   src = eidx;
    const int*   dst = eidx + EE;
    float* out = (float*)d_out;

    // workspace layout (floats)
    float* w = (float*)d_ws;
    float* h_buf   = w;                       // 2097152
    float* gat_buf = h_buf + 2097152;         // 2097152
    float* zdec    = gat_buf + 2097152;       // 2097152
    float* h2      = zdec + 2097152;          // 524288
    float* h2a     = h2 + 524288;             // 524288
    float* gbuf    = h2a + 524288;            // 524288
    float* gabuf   = gbuf + 524288;           // 524288
    float* asrc    = gabuf + 524288;          // 8192
    float* adst    = asrc + 8192;             // 8192
    float* bnsum   = adst + 8192;             // 256
    float* bnsq    = bnsum + 256;             // 256
    float* scale   = bnsq + 256;              // 256
    float* shift   = scale + 256;             // 256
    int*   ideg    = (int*)(shift + 256);     // 8192
    int*   ioff    = ideg + 8192;             // 8192
    int*   icur    = ioff + 8192;             // 8192
    int*   issrc   = icur + 8192;             // 262144
    // readout-phase reuse (after encoders + decoder GEMMs are done):
    float* vsum_part   = h_buf;               // 4*8192*128 = 4194304 floats (h_buf+gat_buf)
    unsigned short* Hcat_bf = (unsigned short*)zdec;   // 8192*128 bf16 = 262144 floats
    float* rowsum_part = zdec + 262144;       // 4*8192 = 32768 floats

    // ---- CSR build (edge_index shared by both encode passes)
    hipMemsetAsync(ideg, 0, 8192 * 4, stream);
    deg_count<<<EE / 256, 256, 0, stream>>>(dst, ideg);
    scan_offsets<<<1, 256, 0, stream>>>(ideg, ioff, icur);
    scatter_edges<<<EE / 256, 256, 0, stream>>>(src, dst, icur, issrc);

    auto encode_pass = [&](const float* x, float* h2_out) {
        // h = x @ W1  (bf16 MFMA, f32 accumulate)
        mfma_gemm<<<dim3(4, 128), 256, 0, stream>>>(x, W1, nullptr, h_buf, NN, HID, IN);
        attn_coeff<<<2048, 256, 0, stream>>>(h_buf, att_src, att_dst, asrc, adst);
        gat_gather<<<2048, 256, 0, stream>>>(issrc, ioff, ideg, asrc, adst, h_buf, gat_buf);
        // h2 = h1 @ W2
        mfma_gemm<<<dim3(1, 128), 256, 0, stream>>>(gat_buf, W2, nullptr, h2_out, NN, OUT, HID);
    };

    encode_pass(feat, h2);
    encode_pass(feat_a, h2a);

    // ---- decoder: h3 = elu(BN(h2 @ Wd1 + bd1)) @ Wd2 + bd2
    sgemm_v2<<<dim3(4, 128, 1), 256, 0, stream>>>(h2, Wd1, bd1, zdec,
                                                  NN, HID, OUT, OUT, 0);
    hipMemsetAsync(bnsum, 0, 512 * 4, stream);
    bn_partial<<<64, 256, 0, stream>>>(zdec, bnsum, bnsq);
    bn_finalize<<<1, 256, 0, stream>>>(bnsum, bnsq, gamma, beta, scale, shift);
    bn_apply_elu<<<2048, 256, 0, stream>>>(zdec, scale, shift);
    mfma_gemm<<<dim3(47, 128), 256, 0, stream>>>(zdec, Wd2, bd2, out + O_H3, NN, IN, HID);

    // ---- readout (zdec free now; h_buf/gat_buf free -> partials)
    pack_hcat_bf<<<4096, 256, 0, stream>>>(h2, h2a, Hcat_bf);
    readout_mfma<<<dim3(128, 4), 256, 0, stream>>>(gneigh, Hcat_bf, vsum_part, rowsum_part);
    readout_norm2<<<8192, 128, 0, stream>>>(vsum_part, rowsum_part, gbuf, gabuf);

    // ---- discriminator
    disc_kernel<<<8192, 128, 0, stream>>>(h2, h2a, gbuf, gabuf, disc_W, disc_b,
                                          out + O_RET, out + O_RETA);

    // ---- copy h2 outputs (slots 0, 4, 5)
    copy_h2<<<2048, 256, 0, stream>>>(h2, h2a, out);
}

// Round 7
// 449.226 us; speedup vs baseline: 9.8425x; 1.5867x over previous
//
#include <hip/hip_runtime.h>
#include <hip/hip_bf16.h>
#include <math.h>

// Problem dims
constexpr int NN  = 8192;
constexpr int EE  = 262144;
constexpr int IN  = 3000;
constexpr int INP = 3008;   // IN padded to mult of 64
constexpr int HID = 256;
constexpr int OUT = 64;

// Output offsets (floats) in d_out: (h2, h3, ret, ret_a, h2, h2_a)
constexpr long O_H2   = 0;
constexpr long O_H3   = 524288;          // 8192*64
constexpr long O_RET  = 25100288;        // + 8192*3000
constexpr long O_RETA = 25116672;        // + 8192*2
constexpr long O_H2B  = 25133056;        // + 8192*2
constexpr long O_H2A  = 25657344;        // + 8192*64

typedef __attribute__((ext_vector_type(8))) short short8v;   // 8 bf16 (4 VGPRs)
typedef __attribute__((ext_vector_type(4))) float f32x4;     // MFMA accumulator

__device__ __forceinline__ short f2bf(float f) {   // RNE f32 -> bf16 bits
    unsigned u = __float_as_uint(f);
    return (short)((u + 0x7FFF + ((u >> 16) & 1)) >> 16);
}

// ================= conversion kernels (one-time per launch) ================================
// feat [8192][3000] f32 -> xb [8192][3008] bf16 (zero-padded tail)
__global__ void cvt_featK(const float* __restrict__ x, unsigned short* __restrict__ xb) {
    long i = (long)blockIdx.x * 256 + threadIdx.x;     // over 8192*376
    int r = (int)(i / 376), c8 = (int)(i % 376) * 8;
    short8v v;
    if (c8 + 8 <= IN) {
        const float* xr = x + (long)r * IN + c8;
        float4 v0 = *reinterpret_cast<const float4*>(xr);
        float4 v1 = *reinterpret_cast<const float4*>(xr + 4);
        v[0]=f2bf(v0.x); v[1]=f2bf(v0.y); v[2]=f2bf(v0.z); v[3]=f2bf(v0.w);
        v[4]=f2bf(v1.x); v[5]=f2bf(v1.y); v[6]=f2bf(v1.z); v[7]=f2bf(v1.w);
    } else {
#pragma unroll
        for (int j = 0; j < 8; ++j)
            v[j] = (c8 + j < IN) ? f2bf(x[(long)r * IN + c8 + j]) : (short)0;
    }
    *reinterpret_cast<short8v*>(xb + (long)r * INP + c8) = v;
}

// W1 [3000][256] -> W1t [256][3008] bf16 (transposed, k-padded)
__global__ void cvt_W1t(const float* __restrict__ W, unsigned short* __restrict__ Wt) {
    int i = blockIdx.x * 256 + threadIdx.x;            // over 256*3008
    int n = i / INP, k = i % INP;
    Wt[i] = (k < IN) ? (unsigned short)f2bf(W[(long)k * HID + n]) : 0;
}

// W2 [256][64] -> W2t [64][256] bf16
__global__ void cvt_W2t(const float* __restrict__ W, unsigned short* __restrict__ Wt) {
    int i = blockIdx.x * 256 + threadIdx.x;            // over 64*256
    int n = i / HID, k = i % HID;
    Wt[i] = (unsigned short)f2bf(W[(long)k * OUT + n]);
}

// Wd2 [256][3000] -> Wd2t [3008][256] bf16 (transposed, n-padded rows)
__global__ void cvt_Wd2t(const float* __restrict__ W, unsigned short* __restrict__ Wt) {
    int i = blockIdx.x * 256 + threadIdx.x;            // over 3008*256
    int n = i / HID, k = i % HID;
    Wt[i] = (n < IN) ? (unsigned short)f2bf(W[(long)k * IN + n]) : 0;
}

// ================= bf16 MFMA GEMM with register-prefetch ===================================
// C[M,N] = A[M,Kp] @ Bt[N][Kp]^T (+bias). BM=BN=64, BK=64, 256 thr (4 waves 2x2).
// A, Bt pre-converted bf16; Kp mult of 64; M mult of 64; Bt has >= gridx*64 rows (padded).
// LDS [64][72] shorts: 144B rows, 16B-aligned b128, ~2-way banks. Single buffer;
// next tile's global loads issued before the MFMA phase (latency hidden under compute).
__global__ __launch_bounds__(256) void mfma_gemm_bf(const unsigned short* __restrict__ A,
                                                    const unsigned short* __restrict__ Bt,
                                                    const float* __restrict__ bias,
                                                    float* __restrict__ C,
                                                    int M, int N, int Kp) {
    __shared__ unsigned short As[64][72];
    __shared__ unsigned short Bs[64][72];
    int t = threadIdx.x, w = t >> 6, l = t & 63;
    int row0 = blockIdx.y * 64, col0 = blockIdx.x * 64;
    int srow = t >> 2, scol = (t & 3) * 16;            // staging: 16 shorts/thread/matrix
    const unsigned short* Ap = A  + (long)(row0 + srow) * Kp + scol;
    const unsigned short* Bp = Bt + (long)(col0 + srow) * Kp + scol;
    int wm = (w >> 1) * 32, wn = (w & 1) * 32;
    int fr = l & 15, fq = l >> 4;                      // fragment row / k-quarter
    int nk = Kp >> 6;

    short8v a0r, a1r, b0r, b1r;
    a0r = *reinterpret_cast<const short8v*>(Ap);
    a1r = *reinterpret_cast<const short8v*>(Ap + 8);
    b0r = *reinterpret_cast<const short8v*>(Bp);
    b1r = *reinterpret_cast<const short8v*>(Bp + 8);

    f32x4 acc[2][2] = {};
    for (int tt = 0; tt < nk; ++tt) {
        *reinterpret_cast<short8v*>(&As[srow][scol])     = a0r;
        *reinterpret_cast<short8v*>(&As[srow][scol + 8]) = a1r;
        *reinterpret_cast<short8v*>(&Bs[srow][scol])     = b0r;
        *reinterpret_cast<short8v*>(&Bs[srow][scol + 8]) = b1r;
        __syncthreads();
        if (tt + 1 < nk) {                             // prefetch next tile into regs
            const unsigned short* Ap2 = Ap + (tt + 1) * 64;
            const unsigned short* Bp2 = Bp + (tt + 1) * 64;
            a0r = *reinterpret_cast<const short8v*>(Ap2);
            a1r = *reinterpret_cast<const short8v*>(Ap2 + 8);
            b0r = *reinterpret_cast<const short8v*>(Bp2);
            b1r = *reinterpret_cast<const short8v*>(Bp2 + 8);
        }
#pragma unroll
        for (int kk = 0; kk < 2; ++kk) {
            short8v fa0 = *reinterpret_cast<const short8v*>(&As[wm + fr][kk * 32 + fq * 8]);
            short8v fa1 = *reinterpret_cast<const short8v*>(&As[wm + 16 + fr][kk * 32 + fq * 8]);
            short8v fb0 = *reinterpret_cast<const short8v*>(&Bs[wn + fr][kk * 32 + fq * 8]);
            short8v fb1 = *reinterpret_cast<const short8v*>(&Bs[wn + 16 + fr][kk * 32 + fq * 8]);
            acc[0][0] = __builtin_amdgcn_mfma_f32_16x16x32_bf16(fa0, fb0, acc[0][0], 0, 0, 0);
            acc[0][1] = __builtin_amdgcn_mfma_f32_16x16x32_bf16(fa0, fb1, acc[0][1], 0, 0, 0);
            acc[1][0] = __builtin_amdgcn_mfma_f32_16x16x32_bf16(fa1, fb0, acc[1][0], 0, 0, 0);
            acc[1][1] = __builtin_amdgcn_mfma_f32_16x16x32_bf16(fa1, fb1, acc[1][1], 0, 0, 0);
        }
        __syncthreads();
    }
    int dc = l & 15;
#pragma unroll
    for (int i = 0; i < 2; ++i)
#pragma unroll
        for (int j = 0; j < 2; ++j) {
            int c = col0 + wn + j * 16 + dc;
            if (c < N) {
                float bb = bias ? bias[c] : 0.f;
#pragma unroll
                for (int q = 0; q < 4; ++q) {
                    int r = row0 + wm + i * 16 + fq * 4 + q;
                    C[(long)r * N + c] = acc[i][j][q] + bb;
                }
            }
        }
}

// ---------------- readout MFMA: vsum[8192,128] = gneigh @ Hcat_bf, fused rowsum ------------
__global__ __launch_bounds__(256) void readout_mfma(const float* __restrict__ gn,
                                                    const unsigned short* __restrict__ Hb,
                                                    float* __restrict__ vsum_part,
                                                    float* __restrict__ rowsum_part) {
    __shared__ short As[64][40];     // [row][k]
    __shared__ short Bs[128][40];    // [col][k]
    __shared__ float rsacc[64][4];
    int t = threadIdx.x;
    int w = t >> 6, l = t & 63;
    int row0 = blockIdx.x * 64;
    int kc   = blockIdx.y;
    int kbeg = kc * 2048;
    int sr = t & 63;
    int sk = (t >> 6) * 8;
    int wm = (w >> 1) * 32, wn = (w & 1) * 64;
    int fr = l & 15, fk = (l >> 4) * 8;
    const float* Arow = gn + (long)(row0 + sr) * NN;

    f32x4 acc[2][4] = {};
    float myrs = 0.f;
    for (int k0 = kbeg; k0 < kbeg + 2048; k0 += 32) {
        {
            float4 v0 = *reinterpret_cast<const float4*>(Arow + k0 + sk);
            float4 v1 = *reinterpret_cast<const float4*>(Arow + k0 + sk + 4);
            short8v av;
            av[0]=f2bf(v0.x); av[1]=f2bf(v0.y); av[2]=f2bf(v0.z); av[3]=f2bf(v0.w);
            av[4]=f2bf(v1.x); av[5]=f2bf(v1.y); av[6]=f2bf(v1.z); av[7]=f2bf(v1.w);
            myrs += v0.x + v0.y + v0.z + v0.w + v1.x + v1.y + v1.z + v1.w;
            *reinterpret_cast<short8v*>(&As[sr][sk]) = av;
        }
#pragma unroll
        for (int cc = 0; cc < 2; ++cc) {
            int col = cc * 64 + sr;
            short8v bv;
#pragma unroll
            for (int i = 0; i < 8; ++i)
                bv[i] = (short)Hb[(long)(k0 + sk + i) * 128 + col];
            *reinterpret_cast<short8v*>(&Bs[col][sk]) = bv;
        }
        __syncthreads();
        short8v a0 = *reinterpret_cast<short8v*>(&As[wm + fr][fk]);
        short8v a1 = *reinterpret_cast<short8v*>(&As[wm + 16 + fr][fk]);
#pragma unroll
        for (int j = 0; j < 4; ++j) {
            short8v bf = *reinterpret_cast<short8v*>(&Bs[wn + j * 16 + fr][fk]);
            acc[0][j] = __builtin_amdgcn_mfma_f32_16x16x32_bf16(a0, bf, acc[0][j], 0, 0, 0);
            acc[1][j] = __builtin_amdgcn_mfma_f32_16x16x32_bf16(a1, bf, acc[1][j], 0, 0, 0);
        }
        __syncthreads();
    }
    rsacc[sr][t >> 6] = myrs;
    __syncthreads();
    if (t < 64)
        rowsum_part[(long)kc * NN + row0 + t] =
            rsacc[t][0] + rsacc[t][1] + rsacc[t][2] + rsacc[t][3];
    int dr = (l >> 4) * 4, dc = l & 15;
#pragma unroll
    for (int i = 0; i < 2; ++i)
#pragma unroll
        for (int j = 0; j < 4; ++j) {
            int c = wn + j * 16 + dc;
#pragma unroll
            for (int q = 0; q < 4; ++q) {
                int r = row0 + wm + i * 16 + dr + q;
                vsum_part[((long)kc * NN + r) * 128 + c] = acc[i][j][q];
            }
        }
}

// ---------------- f32 SGEMM (kept for Wd1: small, feeds BN) -------------------------------
__global__ __launch_bounds__(256) void sgemm_v2(const float* __restrict__ A,
                                                const float* __restrict__ B,
                                                const float* __restrict__ bias,
                                                float* __restrict__ C,
                                                int M, int N, int K,
                                                int kchunk, int atomic_out) {
    __shared__ float As[32][68];
    __shared__ float Bs[32][68];
    int t = threadIdx.x;
    int row0 = blockIdx.y * 64;
    int col0 = blockIdx.x * 64;
    int kbeg = blockIdx.z * kchunk;
    int kend = min(K, kbeg + kchunk);
    int ar  = t & 63;
    int akq = (t >> 6) * 8;
    int bkr = t >> 3;
    int bcq = (t & 7) * 8;
    const float* Arow = A + (long)(row0 + ar) * K;
    int tx4 = (t & 15) * 4, ty4 = (t >> 4) * 4;

    float acc[4][4] = {};
    for (int k0 = kbeg; k0 < kend; k0 += 32) {
        if (k0 + 32 <= kend) {
            float4 v0 = *reinterpret_cast<const float4*>(Arow + k0 + akq);
            float4 v1 = *reinterpret_cast<const float4*>(Arow + k0 + akq + 4);
            As[akq+0][ar]=v0.x; As[akq+1][ar]=v0.y; As[akq+2][ar]=v0.z; As[akq+3][ar]=v0.w;
            As[akq+4][ar]=v1.x; As[akq+5][ar]=v1.y; As[akq+6][ar]=v1.z; As[akq+7][ar]=v1.w;
        } else {
#pragma unroll
            for (int i = 0; i < 8; ++i) {
                int gk = k0 + akq + i;
                As[akq+i][ar] = (gk < kend) ? Arow[gk] : 0.f;
            }
        }
        {
            int gk = k0 + bkr;
            int gc = col0 + bcq;
            if (gk < kend && gc + 8 <= N) {
                const float* Bp = B + (long)gk * N + gc;
                *reinterpret_cast<float4*>(&Bs[bkr][bcq])   = *reinterpret_cast<const float4*>(Bp);
                *reinterpret_cast<float4*>(&Bs[bkr][bcq+4]) = *reinterpret_cast<const float4*>(Bp + 4);
            } else {
#pragma unroll
                for (int i = 0; i < 8; ++i) {
                    int c = gc + i;
                    Bs[bkr][bcq+i] = (gk < kend && c < N) ? B[(long)gk * N + c] : 0.f;
                }
            }
        }
        __syncthreads();
#pragma unroll
        for (int k = 0; k < 32; ++k) {
            float4 a = *reinterpret_cast<const float4*>(&As[k][ty4]);
            float4 b = *reinterpret_cast<const float4*>(&Bs[k][tx4]);
            float av[4] = {a.x, a.y, a.z, a.w};
            float bv[4] = {b.x, b.y, b.z, b.w};
#pragma unroll
            for (int i = 0; i < 4; ++i)
#pragma unroll
                for (int j = 0; j < 4; ++j) acc[i][j] += av[i] * bv[j];
        }
        __syncthreads();
    }
#pragma unroll
    for (int i = 0; i < 4; ++i) {
        int gr = row0 + ty4 + i;
#pragma unroll
        for (int j = 0; j < 4; ++j) {
            int gc = col0 + tx4 + j;
            if (gc < N) {
                long idx = (long)gr * N + gc;
                if (atomic_out) atomicAdd(&C[idx], acc[i][j]);
                else            C[idx] = acc[i][j] + (bias ? bias[gc] : 0.f);
            }
        }
    }
}

// ---------------- CSR build ----------------------------------------------------------------
__global__ void deg_count(const int* __restrict__ dst, int* __restrict__ deg) {
    int i = blockIdx.x * 256 + threadIdx.x;
    if (i < EE) atomicAdd(&deg[dst[i]], 1);
}

__global__ __launch_bounds__(256) void scan_offsets(const int* __restrict__ deg,
                                                    int* __restrict__ off,
                                                    int* __restrict__ cursor) {
    __shared__ int part[256];
    int t = threadIdx.x;
    int base = t * 32;
    int local[32];
    int s = 0;
#pragma unroll
    for (int i = 0; i < 32; ++i) { local[i] = s; s += deg[base + i]; }
    part[t] = s;
    __syncthreads();
    for (int o2 = 1; o2 < 256; o2 <<= 1) {
        int v = (t >= o2) ? part[t - o2] : 0;
        __syncthreads();
        part[t] += v;
        __syncthreads();
    }
    int pre = (t == 0) ? 0 : part[t - 1];
#pragma unroll
    for (int i = 0; i < 32; ++i) {
        int v = pre + local[i];
        off[base + i] = v;
        cursor[base + i] = v;
    }
}

__global__ void scatter_edges(const int* __restrict__ src, const int* __restrict__ dst,
                              int* __restrict__ cursor, int* __restrict__ ssrc) {
    int i = blockIdx.x * 256 + threadIdx.x;
    if (i >= EE) return;
    int slot = atomicAdd(&cursor[dst[i]], 1);
    ssrc[slot] = src[i];
}

// ---------------- attention coefficients ---------------------------------------------------
__global__ void attn_coeff(const float* __restrict__ h, const float* __restrict__ att_src,
                           const float* __restrict__ att_dst, float* __restrict__ a_src,
                           float* __restrict__ a_dst) {
    int wave = threadIdx.x >> 6;
    int lane = threadIdx.x & 63;
    int n = blockIdx.x * 4 + wave;
    float s1 = 0.f, s2 = 0.f;
#pragma unroll
    for (int c = 0; c < 4; ++c) {
        int j = c * 64 + lane;
        float hv = h[(long)n * HID + j];
        s1 += hv * att_src[j];
        s2 += hv * att_dst[j];
    }
    for (int off = 32; off > 0; off >>= 1) {
        s1 += __shfl_down(s1, off);
        s2 += __shfl_down(s2, off);
    }
    if (lane == 0) { a_src[n] = s1; a_dst[n] = s2; }
}

// ---------------- fused GAT gather (bf16 output for the W2 MFMA GEMM) ----------------------
__global__ __launch_bounds__(256) void gat_gather(const int* __restrict__ ssrc,
                                                  const int* __restrict__ off,
                                                  const int* __restrict__ deg,
                                                  const float* __restrict__ asrc,
                                                  const float* __restrict__ adst,
                                                  const float* __restrict__ h,
                                                  unsigned short* __restrict__ gat) {
    int wv = threadIdx.x >> 6, lane = threadIdx.x & 63;
    int d = blockIdx.x * 4 + wv;
    int o = off[d], n = deg[d];
    float ad = adst[d];

    float m = -INFINITY;
    for (int j = lane; j < n; j += 64) {
        float e = asrc[ssrc[o + j]] + ad;
        e = e > 0.f ? e : 0.2f * e;
        m = fmaxf(m, e);
    }
#pragma unroll
    for (int t = 32; t; t >>= 1) m = fmaxf(m, __shfl_xor(m, t));
    float z = 0.f;
    for (int j = lane; j < n; j += 64) {
        float e = asrc[ssrc[o + j]] + ad;
        e = e > 0.f ? e : 0.2f * e;
        z += expf(e - m);
    }
#pragma unroll
    for (int t = 32; t; t >>= 1) z += __shfl_xor(z, t);
    float zinv = 1.0f / (z + 1e-16f);

    float4 acc = {0.f, 0.f, 0.f, 0.f};
    int j = 0;
    for (; j + 2 <= n; j += 2) {
        int s0 = ssrc[o + j], s1 = ssrc[o + j + 1];
        const float4 h0 = *reinterpret_cast<const float4*>(&h[(long)s0 * HID + lane * 4]);
        const float4 h1 = *reinterpret_cast<const float4*>(&h[(long)s1 * HID + lane * 4]);
        float e0 = asrc[s0] + ad; e0 = e0 > 0.f ? e0 : 0.2f * e0;
        float e1 = asrc[s1] + ad; e1 = e1 > 0.f ? e1 : 0.2f * e1;
        float a0 = expf(e0 - m) * zinv;
        float a1 = expf(e1 - m) * zinv;
        acc.x += a0 * h0.x + a1 * h1.x;
        acc.y += a0 * h0.y + a1 * h1.y;
        acc.z += a0 * h0.z + a1 * h1.z;
        acc.w += a0 * h0.w + a1 * h1.w;
    }
    if (j < n) {
        int s0 = ssrc[o + j];
        const float4 h0 = *reinterpret_cast<const float4*>(&h[(long)s0 * HID + lane * 4]);
        float e0 = asrc[s0] + ad; e0 = e0 > 0.f ? e0 : 0.2f * e0;
        float a0 = expf(e0 - m) * zinv;
        acc.x += a0 * h0.x; acc.y += a0 * h0.y; acc.z += a0 * h0.z; acc.w += a0 * h0.w;
    }
    ushort4 r;
    r.x = (unsigned short)f2bf(acc.x > 0.f ? acc.x : expm1f(acc.x));
    r.y = (unsigned short)f2bf(acc.y > 0.f ? acc.y : expm1f(acc.y));
    r.z = (unsigned short)f2bf(acc.z > 0.f ? acc.z : expm1f(acc.z));
    r.w = (unsigned short)f2bf(acc.w > 0.f ? acc.w : expm1f(acc.w));
    *reinterpret_cast<ushort4*>(&gat[(long)d * HID + lane * 4]) = r;
}

// ---------------- batchnorm ----------------------------------------------------------------
__global__ void bn_partial(const float* __restrict__ zd, float* __restrict__ s,
                           float* __restrict__ sq) {
    int t = threadIdx.x;
    float a = 0.f, b = 0.f;
    int r0 = blockIdx.x * 128;
    for (int r = r0; r < r0 + 128; ++r) {
        float v = zd[(long)r * HID + t];
        a += v;
        b += v * v;
    }
    atomicAdd(&s[t], a);
    atomicAdd(&sq[t], b);
}

__global__ void bn_finalize(const float* __restrict__ s, const float* __restrict__ sq,
                            const float* __restrict__ gamma, const float* __restrict__ beta,
                            float* __restrict__ scale, float* __restrict__ shift) {
    int t = threadIdx.x;
    float mean = s[t] / (float)NN;
    float var  = sq[t] / (float)NN - mean * mean;
    float sc   = gamma[t] * rsqrtf(var + 1e-5f);
    scale[t] = sc;
    shift[t] = beta[t] - mean * sc;
}

// BN apply + ELU, emit bf16 A for the Wd2 MFMA GEMM
__global__ void bn_apply_elu_bf(const float* __restrict__ zd, const float* __restrict__ scale,
                                const float* __restrict__ shift, unsigned short* __restrict__ zb) {
    for (long i = (long)blockIdx.x * blockDim.x + threadIdx.x; i < (long)NN * HID;
         i += (long)gridDim.x * blockDim.x) {
        int c = (int)(i & 255);
        float v = zd[i] * scale[c] + shift[c];
        v = v > 0.f ? v : expm1f(v);
        zb[i] = (unsigned short)f2bf(v);
    }
}

// ---------------- readout tail -------------------------------------------------------------
__global__ void pack_hcat_bf(const float* __restrict__ h2, const float* __restrict__ h2a,
                             unsigned short* __restrict__ Hb) {
    int i = blockIdx.x * 256 + threadIdx.x;   // 8192*128 total
    int r = i >> 7, c = i & 127;
    float v = (c < 64) ? h2[(long)r * 64 + c] : h2a[(long)r * 64 + (c - 64)];
    Hb[i] = (unsigned short)f2bf(v);
}

__global__ void readout_norm2(const float* __restrict__ vsum_part,
                              const float* __restrict__ rowsum_part,
                              float* __restrict__ g, float* __restrict__ ga) {
    int r = blockIdx.x;
    int c = threadIdx.x;
    float v = 0.f;
#pragma unroll
    for (int kc = 0; kc < 4; ++kc)
        v += vsum_part[((long)kc * NN + r) * 128 + c];
    float rs = 0.f;
#pragma unroll
    for (int kc = 0; kc < 4; ++kc)
        rs += rowsum_part[(long)kc * NN + r];
    v /= rs;
    int w = c >> 6, lane = c & 63;
    float sq = v * v;
#pragma unroll
    for (int off = 32; off > 0; off >>= 1) sq += __shfl_xor(sq, off);
    float nrm = fmaxf(sqrtf(sq), 1e-12f);
    float out = 1.0f / (1.0f + expf(-(v / nrm)));
    (w == 0 ? g : ga)[(long)r * 64 + lane] = out;
}

// ---------------- discriminator ------------------------------------------------------------
__global__ void disc_kernel(const float* __restrict__ h2, const float* __restrict__ h2a,
                            const float* __restrict__ g, const float* __restrict__ ga,
                            const float* __restrict__ W, const float* __restrict__ b,
                            float* __restrict__ ret, float* __restrict__ reta) {
    int n = blockIdx.x;
    int w = threadIdx.x >> 6, lane = threadIdx.x & 63;
    const float* c = (w == 0) ? g : ga;
    float u = 0.f;
#pragma unroll 8
    for (int e = 0; e < 64; ++e) u += W[lane * 64 + e] * c[(long)n * 64 + e];
    float hp = ((w == 0) ? h2 : h2a)[(long)n * 64 + lane];
    float hm = ((w == 0) ? h2a : h2)[(long)n * 64 + lane];
    float t1 = hp * u, t2 = hm * u;
    for (int off = 32; off > 0; off >>= 1) {
        t1 += __shfl_xor(t1, off);
        t2 += __shfl_xor(t2, off);
    }
    if (lane == 0) {
        float bb = b[0];
        if (w == 0) { ret[n * 2] = t1 + bb;  ret[n * 2 + 1] = t2 + bb; }
        else        { reta[n * 2] = t1 + bb; reta[n * 2 + 1] = t2 + bb; }
    }
}

__global__ void copy_h2(const float* __restrict__ h2, const float* __restrict__ h2a,
                        float* __restrict__ out) {
    int i = blockIdx.x * 256 + threadIdx.x;
    float v = h2[i], va = h2a[i];
    out[O_H2 + i]  = v;
    out[O_H2B + i] = v;
    out[O_H2A + i] = va;
}

// ---------------- driver -------------------------------------------------------------------
extern "C" void kernel_launch(void* const* d_in, const int* in_sizes, int n_in,
                              void* d_out, int out_size, void* d_ws, size_t ws_size,
                              hipStream_t stream) {
    const float* feat    = (const float*)d_in[0];
    const float* feat_a  = (const float*)d_in[1];
    const float* gneigh  = (const float*)d_in[2];
    const float* W1      = (const float*)d_in[3];
    const float* att_src = (const float*)d_in[4];
    const float* att_dst = (const float*)d_in[5];
    const float* W2      = (const float*)d_in[6];
    const float* Wd1     = (const float*)d_in[7];
    const float* bd1     = (const float*)d_in[8];
    const float* gamma   = (const float*)d_in[9];
    const float* beta    = (const float*)d_in[10];
    const float* Wd2     = (const float*)d_in[11];
    const float* bd2     = (const float*)d_in[12];
    const float* disc_W  = (const float*)d_in[13];
    const float* disc_b  = (const float*)d_in[14];
    const int*   eidx    = (const int*)d_in[15];
    const int*   src = eidx;
    const int*   dst = eidx + EE;
    float* out = (float*)d_out;

    // workspace layout (floats)
    float* w = (float*)d_ws;
    float* h_buf   = w;                       // 2097152
    unsigned short* gat_bf = (unsigned short*)(h_buf + 2097152);   // 2097152 sh = 1048576 f
    float* zdec    = h_buf + 2097152 + 1048576;                    // 2097152
    unsigned short* zdec_bf = (unsigned short*)(zdec + 2097152);   // 2097152 sh = 1048576 f
    float* h2      = zdec + 2097152 + 1048576;                     // 524288
    float* h2a     = h2 + 524288;             // 524288
    float* gbuf    = h2a + 524288;            // 524288
    float* gabuf   = gbuf + 524288;           // 524288
    float* asrc    = gabuf + 524288;          // 8192
    float* adst    = asrc + 8192;             // 8192
    float* bnsum   = adst + 8192;             // 256
    float* bnsq    = bnsum + 256;             // 256
    float* scale   = bnsq + 256;              // 256
    float* shift   = scale + 256;             // 256
    unsigned short* W1t  = (unsigned short*)(shift + 256);         // 770048 sh = 385024 f
    unsigned short* W2t  = W1t + 770048;                           // 16384 sh = 8192 f
    unsigned short* Wd2t = W2t + 16384;                            // 770048 sh = 385024 f
    int*   ideg    = (int*)(Wd2t + 770048);   // 8192
    int*   ioff    = ideg + 8192;             // 8192
    int*   icur    = ioff + 8192;             // 8192
    int*   issrc   = icur + 8192;             // 262144
    // readout-phase reuse: h_buf..zdec region free after decoder
    float* vsum_part   = h_buf;               // 4*8192*128 = 4194304 f (spans into zdec)
    unsigned short* Hcat_bf = zdec_bf;        // 262144 sh = 131072 f
    float* rowsum_part = ((float*)zdec_bf) + 131072;               // 32768 f
    // feat bf16 staging lives in the (not-yet-written) h3 region of d_out: 49.3 MB < 98 MB
    unsigned short* fb = (unsigned short*)(out + O_H3);            // [8192][3008] bf16

    // ---- one-time weight conversions (transposed + padded)
    cvt_W1t<<<3008, 256, 0, stream>>>(W1, W1t);
    cvt_W2t<<<64, 256, 0, stream>>>(W2, W2t);
    cvt_Wd2t<<<3008, 256, 0, stream>>>(Wd2, Wd2t);

    // ---- CSR build (edge_index shared by both encode passes)
    hipMemsetAsync(ideg, 0, 8192 * 4, stream);
    deg_count<<<EE / 256, 256, 0, stream>>>(dst, ideg);
    scan_offsets<<<1, 256, 0, stream>>>(ideg, ioff, icur);
    scatter_edges<<<EE / 256, 256, 0, stream>>>(src, dst, icur, issrc);

    auto encode_pass = [&](const float* x, float* h2_out) {
        cvt_featK<<<12032, 256, 0, stream>>>(x, fb);
        mfma_gemm_bf<<<dim3(4, 128), 256, 0, stream>>>(fb, W1t, nullptr, h_buf,
                                                       NN, HID, INP);
        attn_coeff<<<2048, 256, 0, stream>>>(h_buf, att_src, att_dst, asrc, adst);
        gat_gather<<<2048, 256, 0, stream>>>(issrc, ioff, ideg, asrc, adst, h_buf, gat_bf);
        mfma_gemm_bf<<<dim3(1, 128), 256, 0, stream>>>(gat_bf, W2t, nullptr, h2_out,
                                                       NN, OUT, HID);
    };

    encode_pass(feat, h2);
    encode_pass(feat_a, h2a);

    // ---- decoder: h3 = elu(BN(h2 @ Wd1 + bd1)) @ Wd2 + bd2
    sgemm_v2<<<dim3(4, 128, 1), 256, 0, stream>>>(h2, Wd1, bd1, zdec,
                                                  NN, HID, OUT, OUT, 0);
    hipMemsetAsync(bnsum, 0, 512 * 4, stream);
    bn_partial<<<64, 256, 0, stream>>>(zdec, bnsum, bnsq);
    bn_finalize<<<1, 256, 0, stream>>>(bnsum, bnsq, gamma, beta, scale, shift);
    bn_apply_elu_bf<<<2048, 256, 0, stream>>>(zdec, scale, shift, zdec_bf);
    mfma_gemm_bf<<<dim3(47, 128), 256, 0, stream>>>(zdec_bf, Wd2t, bd2, out + O_H3,
                                                    NN, IN, HID);

    // ---- readout
    pack_hcat_bf<<<4096, 256, 0, stream>>>(h2, h2a, Hcat_bf);
    readout_mfma<<<dim3(128, 4), 256, 0, stream>>>(gneigh, Hcat_bf, vsum_part, rowsum_part);
    readout_norm2<<<8192, 128, 0, stream>>>(vsum_part, rowsum_part, gbuf, gabuf);

    // ---- discriminator
    disc_kernel<<<8192, 128, 0, stream>>>(h2, h2a, gbuf, gabuf, disc_W, disc_b,
                                          out + O_RET, out + O_RETA);

    // ---- copy h2 outputs (slots 0, 4, 5)
    copy_h2<<<2048, 256, 0, stream>>>(h2, h2a, out);
}

// Round 8
// 435.922 us; speedup vs baseline: 10.1429x; 1.0305x over previous
//
#include <hip/hip_runtime.h>
#include <hip/hip_bf16.h>
#include <math.h>

// Problem dims
constexpr int NN  = 8192;
constexpr int EE  = 262144;
constexpr int IN  = 3000;
constexpr int INP = 3008;   // IN padded to mult of 64
constexpr int HID = 256;
constexpr int OUT = 64;

// Output offsets (floats) in d_out: (h2, h3, ret, ret_a, h2, h2_a)
constexpr long O_H2   = 0;
constexpr long O_H3   = 524288;          // 8192*64
constexpr long O_RET  = 25100288;        // + 8192*3000
constexpr long O_RETA = 25116672;        // + 8192*2
constexpr long O_H2B  = 25133056;        // + 8192*2
constexpr long O_H2A  = 25657344;        // + 8192*64

typedef __attribute__((ext_vector_type(8))) short short8v;   // 8 bf16 (4 VGPRs)
typedef __attribute__((ext_vector_type(4))) float f32x4;     // MFMA accumulator

__device__ __forceinline__ short f2bf(float f) {   // RNE f32 -> bf16 bits
    unsigned u = __float_as_uint(f);
    return (short)((u + 0x7FFF + ((u >> 16) & 1)) >> 16);
}
__device__ __forceinline__ float bf2f(unsigned short u) {
    return __uint_as_float(((unsigned)u) << 16);
}

// ================= conversion kernels (one-time per launch) ================================
// feat [8192][3000] f32 -> xb [8192][3008] bf16 (zero-padded tail)
__global__ void cvt_featK(const float* __restrict__ x, unsigned short* __restrict__ xb) {
    long i = (long)blockIdx.x * 256 + threadIdx.x;     // over 8192*376
    int r = (int)(i / 376), c8 = (int)(i % 376) * 8;
    short8v v;
    if (c8 + 8 <= IN) {
        const float* xr = x + (long)r * IN + c8;
        float4 v0 = *reinterpret_cast<const float4*>(xr);
        float4 v1 = *reinterpret_cast<const float4*>(xr + 4);
        v[0]=f2bf(v0.x); v[1]=f2bf(v0.y); v[2]=f2bf(v0.z); v[3]=f2bf(v0.w);
        v[4]=f2bf(v1.x); v[5]=f2bf(v1.y); v[6]=f2bf(v1.z); v[7]=f2bf(v1.w);
    } else {
#pragma unroll
        for (int j = 0; j < 8; ++j)
            v[j] = (c8 + j < IN) ? f2bf(x[(long)r * IN + c8 + j]) : (short)0;
    }
    *reinterpret_cast<short8v*>(xb + (long)r * INP + c8) = v;
}

// W1 [3000][256] -> W1t [256][3008] bf16 (transposed, k-padded)
__global__ void cvt_W1t(const float* __restrict__ W, unsigned short* __restrict__ Wt) {
    int i = blockIdx.x * 256 + threadIdx.x;            // over 256*3008
    int n = i / INP, k = i % INP;
    Wt[i] = (k < IN) ? (unsigned short)f2bf(W[(long)k * HID + n]) : 0;
}

// W2 [256][64] -> W2t [64][256] bf16
__global__ void cvt_W2t(const float* __restrict__ W, unsigned short* __restrict__ Wt) {
    int i = blockIdx.x * 256 + threadIdx.x;            // over 64*256
    int n = i / HID, k = i % HID;
    Wt[i] = (unsigned short)f2bf(W[(long)k * OUT + n]);
}

// Wd1 [64][256] -> Wd1t [256][64] bf16
__global__ void cvt_Wd1t(const float* __restrict__ W, unsigned short* __restrict__ Wt) {
    int i = blockIdx.x * 256 + threadIdx.x;            // over 256*64
    int n = i / OUT, k = i % OUT;
    Wt[i] = (unsigned short)f2bf(W[(long)k * HID + n]);
}

// Wd2 [256][3000] -> Wd2t [3008][256] bf16 (transposed, n-padded rows)
__global__ void cvt_Wd2t(const float* __restrict__ W, unsigned short* __restrict__ Wt) {
    int i = blockIdx.x * 256 + threadIdx.x;            // over 3008*256
    int n = i / HID, k = i % HID;
    Wt[i] = (n < IN) ? (unsigned short)f2bf(W[(long)k * IN + n]) : 0;
}

// ================= bf16 MFMA GEMM with register-prefetch ===================================
// C[M,N] = A[M,Kp] @ Bt[N][Kp]^T (+bias). BM=BN=64, BK=64, 256 thr (4 waves 2x2).
// C (f32) and/or Cb (bf16) destinations; either may be null.
__global__ __launch_bounds__(256) void mfma_gemm_bf(const unsigned short* __restrict__ A,
                                                    const unsigned short* __restrict__ Bt,
                                                    const float* __restrict__ bias,
                                                    float* __restrict__ C,
                                                    unsigned short* __restrict__ Cb,
                                                    int M, int N, int Kp) {
    __shared__ unsigned short As[64][72];
    __shared__ unsigned short Bs[64][72];
    int t = threadIdx.x, w = t >> 6, l = t & 63;
    int row0 = blockIdx.y * 64, col0 = blockIdx.x * 64;
    int srow = t >> 2, scol = (t & 3) * 16;            // staging: 16 shorts/thread/matrix
    const unsigned short* Ap = A  + (long)(row0 + srow) * Kp + scol;
    const unsigned short* Bp = Bt + (long)(col0 + srow) * Kp + scol;
    int wm = (w >> 1) * 32, wn = (w & 1) * 32;
    int fr = l & 15, fq = l >> 4;                      // fragment row / k-quarter
    int nk = Kp >> 6;

    short8v a0r, a1r, b0r, b1r;
    a0r = *reinterpret_cast<const short8v*>(Ap);
    a1r = *reinterpret_cast<const short8v*>(Ap + 8);
    b0r = *reinterpret_cast<const short8v*>(Bp);
    b1r = *reinterpret_cast<const short8v*>(Bp + 8);

    f32x4 acc[2][2] = {};
    for (int tt = 0; tt < nk; ++tt) {
        *reinterpret_cast<short8v*>(&As[srow][scol])     = a0r;
        *reinterpret_cast<short8v*>(&As[srow][scol + 8]) = a1r;
        *reinterpret_cast<short8v*>(&Bs[srow][scol])     = b0r;
        *reinterpret_cast<short8v*>(&Bs[srow][scol + 8]) = b1r;
        __syncthreads();
        if (tt + 1 < nk) {                             // prefetch next tile into regs
            const unsigned short* Ap2 = Ap + (tt + 1) * 64;
            const unsigned short* Bp2 = Bp + (tt + 1) * 64;
            a0r = *reinterpret_cast<const short8v*>(Ap2);
            a1r = *reinterpret_cast<const short8v*>(Ap2 + 8);
            b0r = *reinterpret_cast<const short8v*>(Bp2);
            b1r = *reinterpret_cast<const short8v*>(Bp2 + 8);
        }
#pragma unroll
        for (int kk = 0; kk < 2; ++kk) {
            short8v fa0 = *reinterpret_cast<const short8v*>(&As[wm + fr][kk * 32 + fq * 8]);
            short8v fa1 = *reinterpret_cast<const short8v*>(&As[wm + 16 + fr][kk * 32 + fq * 8]);
            short8v fb0 = *reinterpret_cast<const short8v*>(&Bs[wn + fr][kk * 32 + fq * 8]);
            short8v fb1 = *reinterpret_cast<const short8v*>(&Bs[wn + 16 + fr][kk * 32 + fq * 8]);
            acc[0][0] = __builtin_amdgcn_mfma_f32_16x16x32_bf16(fa0, fb0, acc[0][0], 0, 0, 0);
            acc[0][1] = __builtin_amdgcn_mfma_f32_16x16x32_bf16(fa0, fb1, acc[0][1], 0, 0, 0);
            acc[1][0] = __builtin_amdgcn_mfma_f32_16x16x32_bf16(fa1, fb0, acc[1][0], 0, 0, 0);
            acc[1][1] = __builtin_amdgcn_mfma_f32_16x16x32_bf16(fa1, fb1, acc[1][1], 0, 0, 0);
        }
        __syncthreads();
    }
    int dc = l & 15;
#pragma unroll
    for (int i = 0; i < 2; ++i)
#pragma unroll
        for (int j = 0; j < 2; ++j) {
            int c = col0 + wn + j * 16 + dc;
            if (c < N) {
                float bb = bias ? bias[c] : 0.f;
#pragma unroll
                for (int q = 0; q < 4; ++q) {
                    int r = row0 + wm + i * 16 + fq * 4 + q;
                    float v = acc[i][j][q] + bb;
                    long idx = (long)r * N + c;
                    if (C)  C[idx]  = v;
                    if (Cb) Cb[idx] = (unsigned short)f2bf(v);
                }
            }
        }
}

// ---------------- readout MFMA v2: prefetched, transposed-B ---------------------------------
// vsum[8192,128] = gneigh[8192,8192] @ HcatT^T, HcatT[128][8192] bf16. Fused rowsum.
// BM=64, BN=128, BK=64, split-K=4 (kchunk 2048), per-chunk partial outputs.
__global__ __launch_bounds__(256) void readout_mfma2(const float* __restrict__ gn,
                                                     const unsigned short* __restrict__ HT,
                                                     float* __restrict__ vsum_part,
                                                     float* __restrict__ rowsum_part) {
    __shared__ unsigned short As[64][72];
    __shared__ unsigned short Bs[128][72];
    __shared__ float rsacc[64][4];
    int t = threadIdx.x, w = t >> 6, l = t & 63;
    int row0 = blockIdx.x * 64;
    int kc = blockIdx.y, kbeg = kc * 2048;
    int asr = t >> 2, asc = (t & 3) * 16;              // A: 16 f32 / thread
    int bsr = t >> 1, bsc = (t & 1) * 32;              // B: 32 bf16 / thread
    const float*          Ap = gn + (long)(row0 + asr) * NN + kbeg + asc;
    const unsigned short* Bp = HT + (long)bsr * NN + kbeg + bsc;
    int wm = (w >> 1) * 32, wn = (w & 1) * 64;
    int fr = l & 15, fq = l >> 4;

    float4  a4[4];
    short8v b8[4];
#pragma unroll
    for (int q = 0; q < 4; ++q) a4[q] = *reinterpret_cast<const float4*>(Ap + q * 4);
#pragma unroll
    for (int q = 0; q < 4; ++q) b8[q] = *reinterpret_cast<const short8v*>(Bp + q * 8);

    f32x4 acc[2][4] = {};
    float myrs = 0.f;
    for (int it = 0; it < 32; ++it) {
#pragma unroll
        for (int q = 0; q < 4; ++q) {
            float4 v = a4[q];
            ushort4 s;
            s.x = (unsigned short)f2bf(v.x);
            s.y = (unsigned short)f2bf(v.y);
            s.z = (unsigned short)f2bf(v.z);
            s.w = (unsigned short)f2bf(v.w);
            *reinterpret_cast<ushort4*>(&As[asr][asc + q * 4]) = s;
            myrs += v.x + v.y + v.z + v.w;
        }
#pragma unroll
        for (int q = 0; q < 4; ++q)
            *reinterpret_cast<short8v*>(&Bs[bsr][bsc + q * 8]) = b8[q];
        __syncthreads();
        if (it + 1 < 32) {                             // prefetch next K-tile
            const float*          Ap2 = Ap + (it + 1) * 64;
            const unsigned short* Bp2 = Bp + (it + 1) * 64;
#pragma unroll
            for (int q = 0; q < 4; ++q) a4[q] = *reinterpret_cast<const float4*>(Ap2 + q * 4);
#pragma unroll
            for (int q = 0; q < 4; ++q) b8[q] = *reinterpret_cast<const short8v*>(Bp2 + q * 8);
        }
#pragma unroll
        for (int kk = 0; kk < 2; ++kk) {
            short8v fa0 = *reinterpret_cast<const short8v*>(&As[wm + fr][kk * 32 + fq * 8]);
            short8v fa1 = *reinterpret_cast<const short8v*>(&As[wm + 16 + fr][kk * 32 + fq * 8]);
#pragma unroll
            for (int j = 0; j < 4; ++j) {
                short8v fb = *reinterpret_cast<const short8v*>(&Bs[wn + j * 16 + fr][kk * 32 + fq * 8]);
                acc[0][j] = __builtin_amdgcn_mfma_f32_16x16x32_bf16(fa0, fb, acc[0][j], 0, 0, 0);
                acc[1][j] = __builtin_amdgcn_mfma_f32_16x16x32_bf16(fa1, fb, acc[1][j], 0, 0, 0);
            }
        }
        __syncthreads();
    }
    rsacc[asr][t & 3] = myrs;
    __syncthreads();
    if (t < 64)
        rowsum_part[(long)kc * NN + row0 + t] =
            rsacc[t][0] + rsacc[t][1] + rsacc[t][2] + rsacc[t][3];
    int dc = l & 15;
#pragma unroll
    for (int i = 0; i < 2; ++i)
#pragma unroll
        for (int j = 0; j < 4; ++j) {
            int c = wn + j * 16 + dc;
#pragma unroll
            for (int q = 0; q < 4; ++q) {
                int r = row0 + wm + i * 16 + fq * 4 + q;
                vsum_part[((long)kc * NN + r) * 128 + c] = acc[i][j][q];
            }
        }
}

// ---------------- CSR build ----------------------------------------------------------------
__global__ void deg_count(const int* __restrict__ dst, int* __restrict__ deg) {
    int i = blockIdx.x * 256 + threadIdx.x;
    if (i < EE) atomicAdd(&deg[dst[i]], 1);
}

__global__ __launch_bounds__(256) void scan_offsets(const int* __restrict__ deg,
                                                    int* __restrict__ off,
                                                    int* __restrict__ cursor) {
    __shared__ int part[256];
    int t = threadIdx.x;
    int base = t * 32;
    int local[32];
    int s = 0;
#pragma unroll
    for (int i = 0; i < 32; ++i) { local[i] = s; s += deg[base + i]; }
    part[t] = s;
    __syncthreads();
    for (int o2 = 1; o2 < 256; o2 <<= 1) {
        int v = (t >= o2) ? part[t - o2] : 0;
        __syncthreads();
        part[t] += v;
        __syncthreads();
    }
    int pre = (t == 0) ? 0 : part[t - 1];
#pragma unroll
    for (int i = 0; i < 32; ++i) {
        int v = pre + local[i];
        off[base + i] = v;
        cursor[base + i] = v;
    }
}

__global__ void scatter_edges(const int* __restrict__ src, const int* __restrict__ dst,
                              int* __restrict__ cursor, int* __restrict__ ssrc) {
    int i = blockIdx.x * 256 + threadIdx.x;
    if (i >= EE) return;
    int slot = atomicAdd(&cursor[dst[i]], 1);
    ssrc[slot] = src[i];
}

// ---------------- attention coefficients (bf16 h) ------------------------------------------
__global__ void attn_coeff_bf(const unsigned short* __restrict__ h,
                              const float* __restrict__ att_src,
                              const float* __restrict__ att_dst,
                              float* __restrict__ a_src, float* __restrict__ a_dst) {
    int wave = threadIdx.x >> 6, lane = threadIdx.x & 63;
    int n = blockIdx.x * 4 + wave;
    ushort4 hv = *reinterpret_cast<const ushort4*>(&h[(long)n * HID + lane * 4]);
    float4 vs = *reinterpret_cast<const float4*>(&att_src[lane * 4]);
    float4 vd = *reinterpret_cast<const float4*>(&att_dst[lane * 4]);
    float h0 = bf2f(hv.x), h1 = bf2f(hv.y), h2v = bf2f(hv.z), h3v = bf2f(hv.w);
    float s1 = h0 * vs.x + h1 * vs.y + h2v * vs.z + h3v * vs.w;
    float s2 = h0 * vd.x + h1 * vd.y + h2v * vd.z + h3v * vd.w;
#pragma unroll
    for (int off = 32; off > 0; off >>= 1) {
        s1 += __shfl_down(s1, off);
        s2 += __shfl_down(s2, off);
    }
    if (lane == 0) { a_src[n] = s1; a_dst[n] = s2; }
}

// ---------------- fused GAT gather (bf16 h in, bf16 gat out) -------------------------------
__global__ __launch_bounds__(256) void gat_gather(const int* __restrict__ ssrc,
                                                  const int* __restrict__ off,
                                                  const int* __restrict__ deg,
                                                  const float* __restrict__ asrc,
                                                  const float* __restrict__ adst,
                                                  const unsigned short* __restrict__ h,
                                                  unsigned short* __restrict__ gat) {
    int wv = threadIdx.x >> 6, lane = threadIdx.x & 63;
    int d = blockIdx.x * 4 + wv;
    int o = off[d], n = deg[d];
    float ad = adst[d];

    float m = -INFINITY;
    for (int j = lane; j < n; j += 64) {
        float e = asrc[ssrc[o + j]] + ad;
        e = e > 0.f ? e : 0.2f * e;
        m = fmaxf(m, e);
    }
#pragma unroll
    for (int t = 32; t; t >>= 1) m = fmaxf(m, __shfl_xor(m, t));
    float z = 0.f;
    for (int j = lane; j < n; j += 64) {
        float e = asrc[ssrc[o + j]] + ad;
        e = e > 0.f ? e : 0.2f * e;
        z += expf(e - m);
    }
#pragma unroll
    for (int t = 32; t; t >>= 1) z += __shfl_xor(z, t);
    float zinv = 1.0f / (z + 1e-16f);

    float4 acc = {0.f, 0.f, 0.f, 0.f};
    int j = 0;
    for (; j + 2 <= n; j += 2) {
        int s0 = ssrc[o + j], s1 = ssrc[o + j + 1];
        const ushort4 h0 = *reinterpret_cast<const ushort4*>(&h[(long)s0 * HID + lane * 4]);
        const ushort4 h1 = *reinterpret_cast<const ushort4*>(&h[(long)s1 * HID + lane * 4]);
        float e0 = asrc[s0] + ad; e0 = e0 > 0.f ? e0 : 0.2f * e0;
        float e1 = asrc[s1] + ad; e1 = e1 > 0.f ? e1 : 0.2f * e1;
        float a0 = expf(e0 - m) * zinv;
        float a1 = expf(e1 - m) * zinv;
        acc.x += a0 * bf2f(h0.x) + a1 * bf2f(h1.x);
        acc.y += a0 * bf2f(h0.y) + a1 * bf2f(h1.y);
        acc.z += a0 * bf2f(h0.z) + a1 * bf2f(h1.z);
        acc.w += a0 * bf2f(h0.w) + a1 * bf2f(h1.w);
    }
    if (j < n) {
        int s0 = ssrc[o + j];
        const ushort4 h0 = *reinterpret_cast<const ushort4*>(&h[(long)s0 * HID + lane * 4]);
        float e0 = asrc[s0] + ad; e0 = e0 > 0.f ? e0 : 0.2f * e0;
        float a0 = expf(e0 - m) * zinv;
        acc.x += a0 * bf2f(h0.x); acc.y += a0 * bf2f(h0.y);
        acc.z += a0 * bf2f(h0.z); acc.w += a0 * bf2f(h0.w);
    }
    ushort4 r;
    r.x = (unsigned short)f2bf(acc.x > 0.f ? acc.x : expm1f(acc.x));
    r.y = (unsigned short)f2bf(acc.y > 0.f ? acc.y : expm1f(acc.y));
    r.z = (unsigned short)f2bf(acc.z > 0.f ? acc.z : expm1f(acc.z));
    r.w = (unsigned short)f2bf(acc.w > 0.f ? acc.w : expm1f(acc.w));
    *reinterpret_cast<ushort4*>(&gat[(long)d * HID + lane * 4]) = r;
}

// ---------------- batchnorm ----------------------------------------------------------------
__global__ void bn_partial(const float* __restrict__ zd, float* __restrict__ s,
                           float* __restrict__ sq) {
    int t = threadIdx.x;
    float a = 0.f, b = 0.f;
    int r0 = blockIdx.x * 128;
    for (int r = r0; r < r0 + 128; ++r) {
        float v = zd[(long)r * HID + t];
        a += v;
        b += v * v;
    }
    atomicAdd(&s[t], a);
    atomicAdd(&sq[t], b);
}

__global__ void bn_finalize(const float* __restrict__ s, const float* __restrict__ sq,
                            const float* __restrict__ gamma, const float* __restrict__ beta,
                            float* __restrict__ scale, float* __restrict__ shift) {
    int t = threadIdx.x;
    float mean = s[t] / (float)NN;
    float var  = sq[t] / (float)NN - mean * mean;
    float sc   = gamma[t] * rsqrtf(var + 1e-5f);
    scale[t] = sc;
    shift[t] = beta[t] - mean * sc;
}

__global__ void bn_apply_elu_bf(const float* __restrict__ zd, const float* __restrict__ scale,
                                const float* __restrict__ shift, unsigned short* __restrict__ zb) {
    for (long i = (long)blockIdx.x * blockDim.x + threadIdx.x; i < (long)NN * HID;
         i += (long)gridDim.x * blockDim.x) {
        int c = (int)(i & 255);
        float v = zd[i] * scale[c] + shift[c];
        v = v > 0.f ? v : expm1f(v);
        zb[i] = (unsigned short)f2bf(v);
    }
}

// ---------------- readout tail -------------------------------------------------------------
// HcatT[128][8192] bf16: row c<64 from h2[:,c], else h2a[:,c-64]
__global__ void pack_hcatT(const float* __restrict__ h2, const float* __restrict__ h2a,
                           unsigned short* __restrict__ HT) {
    int c = blockIdx.x;                  // 0..127
    int r = blockIdx.y * 256 + threadIdx.x;
    float v = (c < 64) ? h2[(long)r * 64 + c] : h2a[(long)r * 64 + (c - 64)];
    HT[(long)c * NN + r] = (unsigned short)f2bf(v);
}

__global__ void readout_norm2(const float* __restrict__ vsum_part,
                              const float* __restrict__ rowsum_part,
                              float* __restrict__ g, float* __restrict__ ga) {
    int r = blockIdx.x;
    int c = threadIdx.x;
    float v = 0.f;
#pragma unroll
    for (int kc = 0; kc < 4; ++kc)
        v += vsum_part[((long)kc * NN + r) * 128 + c];
    float rs = 0.f;
#pragma unroll
    for (int kc = 0; kc < 4; ++kc)
        rs += rowsum_part[(long)kc * NN + r];
    v /= rs;
    int w = c >> 6, lane = c & 63;
    float sq = v * v;
#pragma unroll
    for (int off = 32; off > 0; off >>= 1) sq += __shfl_xor(sq, off);
    float nrm = fmaxf(sqrtf(sq), 1e-12f);
    float out = 1.0f / (1.0f + expf(-(v / nrm)));
    (w == 0 ? g : ga)[(long)r * 64 + lane] = out;
}

// ---------------- discriminator ------------------------------------------------------------
__global__ void disc_kernel(const float* __restrict__ h2, const float* __restrict__ h2a,
                            const float* __restrict__ g, const float* __restrict__ ga,
                            const float* __restrict__ W, const float* __restrict__ b,
                            float* __restrict__ ret, float* __restrict__ reta) {
    int n = blockIdx.x;
    int w = threadIdx.x >> 6, lane = threadIdx.x & 63;
    const float* c = (w == 0) ? g : ga;
    float u = 0.f;
#pragma unroll 8
    for (int e = 0; e < 64; ++e) u += W[lane * 64 + e] * c[(long)n * 64 + e];
    float hp = ((w == 0) ? h2 : h2a)[(long)n * 64 + lane];
    float hm = ((w == 0) ? h2a : h2)[(long)n * 64 + lane];
    float t1 = hp * u, t2 = hm * u;
    for (int off = 32; off > 0; off >>= 1) {
        t1 += __shfl_xor(t1, off);
        t2 += __shfl_xor(t2, off);
    }
    if (lane == 0) {
        float bb = b[0];
        if (w == 0) { ret[n * 2] = t1 + bb;  ret[n * 2 + 1] = t2 + bb; }
        else        { reta[n * 2] = t1 + bb; reta[n * 2 + 1] = t2 + bb; }
    }
}

__global__ void copy_h2(const float* __restrict__ h2, const float* __restrict__ h2a,
                        float* __restrict__ out) {
    int i = blockIdx.x * 256 + threadIdx.x;
    float v = h2[i], va = h2a[i];
    out[O_H2 + i]  = v;
    out[O_H2B + i] = v;
    out[O_H2A + i] = va;
}

// ---------------- driver -------------------------------------------------------------------
extern "C" void kernel_launch(void* const* d_in, const int* in_sizes, int n_in,
                              void* d_out, int out_size, void* d_ws, size_t ws_size,
                              hipStream_t stream) {
    const float* feat    = (const float*)d_in[0];
    const float* feat_a  = (const float*)d_in[1];
    const float* gneigh  = (const float*)d_in[2];
    const float* W1      = (const float*)d_in[3];
    const float* att_src = (const float*)d_in[4];
    const float* att_dst = (const float*)d_in[5];
    const float* W2      = (const float*)d_in[6];
    const float* Wd1     = (const float*)d_in[7];
    const float* bd1     = (const float*)d_in[8];
    const float* gamma   = (const float*)d_in[9];
    const float* beta    = (const float*)d_in[10];
    const float* Wd2     = (const float*)d_in[11];
    const float* bd2     = (const float*)d_in[12];
    const float* disc_W  = (const float*)d_in[13];
    const float* disc_b  = (const float*)d_in[14];
    const int*   eidx    = (const int*)d_in[15];
    const int*   src = eidx;
    const int*   dst = eidx + EE;
    float* out = (float*)d_out;

    // workspace layout (floats)
    float* w = (float*)d_ws;
    float* h_buf   = w;                                            // 2097152 f (8 MB)
    unsigned short* h_bf = (unsigned short*)h_buf;                 // 8192*256 bf16 (4 MB)
    unsigned short* gat_bf = (unsigned short*)(h_buf + 2097152);   // 4 MB
    float* zdec    = h_buf + 2097152 + 1048576;                    // 2097152 f (8 MB)
    unsigned short* zdec_bf = (unsigned short*)(zdec + 2097152);   // 4 MB
    float* h2      = zdec + 2097152 + 1048576;                     // 524288
    float* h2a     = h2 + 524288;             // 524288
    float* gbuf    = h2a + 524288;            // 524288
    float* gabuf   = gbuf + 524288;           // 524288
    unsigned short* h2b = (unsigned short*)(gabuf + 524288);       // 8192*64 bf16 (1 MB = 262144 f)
    float* asrc    = gabuf + 524288 + 262144; // 8192
    float* adst    = asrc + 8192;             // 8192
    float* bnsum   = adst + 8192;             // 256
    float* bnsq    = bnsum + 256;             // 256
    float* scale   = bnsq + 256;              // 256
    float* shift   = scale + 256;             // 256
    unsigned short* W1t  = (unsigned short*)(shift + 256);         // 770048 sh
    unsigned short* W2t  = W1t + 770048;                           // 16384 sh
    unsigned short* Wd1t = W2t + 16384;                            // 16384 sh
    unsigned short* Wd2t = Wd1t + 16384;                           // 770048 sh
    int*   ideg    = (int*)(Wd2t + 770048);   // 8192
    int*   ioff    = ideg + 8192;             // 8192
    int*   icur    = ioff + 8192;             // 8192
    int*   issrc   = icur + 8192;             // 262144
    // readout-phase reuse (h_buf..zdec dead after decoder):
    float* vsum_part = h_buf;                 // 4*8192*128 f = 16 MB (h_buf+gat_bf+zdec head)
    unsigned short* HT = zdec_bf;             // 128*8192 bf16 = 2 MB
    float* rowsum_part = ((float*)zdec_bf) + 524288;               // 4*8192 f
    // feat bf16 staging in the not-yet-written h3 region of d_out (49.3 MB < 96 MB)
    unsigned short* fb = (unsigned short*)(out + O_H3);            // [8192][3008] bf16

    // ---- one-time weight conversions (transposed + padded)
    cvt_W1t<<<3008, 256, 0, stream>>>(W1, W1t);
    cvt_W2t<<<64, 256, 0, stream>>>(W2, W2t);
    cvt_Wd1t<<<64, 256, 0, stream>>>(Wd1, Wd1t);
    cvt_Wd2t<<<3008, 256, 0, stream>>>(Wd2, Wd2t);

    // ---- CSR build (edge_index shared by both encode passes)
    hipMemsetAsync(ideg, 0, 8192 * 4, stream);
    deg_count<<<EE / 256, 256, 0, stream>>>(dst, ideg);
    scan_offsets<<<1, 256, 0, stream>>>(ideg, ioff, icur);
    scatter_edges<<<EE / 256, 256, 0, stream>>>(src, dst, icur, issrc);

    auto encode_pass = [&](const float* x, float* h2_out) {
        cvt_featK<<<12032, 256, 0, stream>>>(x, fb);
        // h = x @ W1 -> bf16 h directly
        mfma_gemm_bf<<<dim3(4, 128), 256, 0, stream>>>(fb, W1t, nullptr,
                                                       nullptr, h_bf, NN, HID, INP);
        attn_coeff_bf<<<2048, 256, 0, stream>>>(h_bf, att_src, att_dst, asrc, adst);
        gat_gather<<<2048, 256, 0, stream>>>(issrc, ioff, ideg, asrc, adst, h_bf, gat_bf);
        // h2 = h1 @ W2 -> f32 h2 (+ bf16 h2b for the Wd1 GEMM)
        mfma_gemm_bf<<<dim3(1, 128), 256, 0, stream>>>(gat_bf, W2t, nullptr,
                                                       h2_out, h2b, NN, OUT, HID);
    };

    encode_pass(feat, h2);       // leaves h2b = bf16(h2)
    float* h2b_keep_marker = nullptr; (void)h2b_keep_marker;
    // NOTE: h2b must correspond to h2 (first pass) for the decoder; second pass overwrites
    // h2b with bf16(h2a), so run the decoder's Wd1 GEMM input from a dedicated copy order:
    // simplest correct order: run pass A, save h2b? Instead: run pass for feat_a FIRST,
    // then feat, so h2b ends as bf16(h2). (reference decoder uses h2 only)
    // -- implemented below by ordering --
    encode_pass(feat_a, h2a);
    // h2b now holds bf16(h2a); recompute bf16(h2) cheaply via pack into h2b:
    // (1 MB transform, trivial)
    {
        // reuse pack: convert h2 f32 -> h2b bf16
        // simple elementwise kernel inline via bn_apply path is overkill; use cvt lambda:
    }
    // elementwise f32->bf16 for h2 (524288 elems)
    // (defined as a tiny kernel below via cvt_h2b)
    extern __global__ void cvt_h2b_decl();  // (placeholder, real kernel below)
    // actual launch happens after kernel definition — see cvt_h2b
    void(0);
    // ---- decoder: h3 = elu(BN(h2 @ Wd1 + bd1)) @ Wd2 + bd2
    {
        // convert h2 -> h2b (bf16)
        struct L { static __global__ void k(const float* __restrict__ a,
                                            unsigned short* __restrict__ b) {
            int i = blockIdx.x * 256 + threadIdx.x;
            b[i] = (unsigned short)f2bf(a[i]);
        }};
        L::k<<<2048, 256, 0, stream>>>(h2, h2b);
    }
    mfma_gemm_bf<<<dim3(4, 128), 256, 0, stream>>>(h2b, Wd1t, bd1,
                                                   zdec, nullptr, NN, HID, OUT);
    hipMemsetAsync(bnsum, 0, 512 * 4, stream);
    bn_partial<<<64, 256, 0, stream>>>(zdec, bnsum, bnsq);
    bn_finalize<<<1, 256, 0, stream>>>(bnsum, bnsq, gamma, beta, scale, shift);
    bn_apply_elu_bf<<<2048, 256, 0, stream>>>(zdec, scale, shift, zdec_bf);
    mfma_gemm_bf<<<dim3(47, 128), 256, 0, stream>>>(zdec_bf, Wd2t, bd2,
                                                    out + O_H3, nullptr, NN, IN, HID);

    // ---- readout (zdec_bf region free now -> HT)
    pack_hcatT<<<dim3(128, 32), 256, 0, stream>>>(h2, h2a, HT);
    readout_mfma2<<<dim3(128, 4), 256, 0, stream>>>(gneigh, HT, vsum_part, rowsum_part);
    readout_norm2<<<8192, 128, 0, stream>>>(vsum_part, rowsum_part, gbuf, gabuf);

    // ---- discriminator
    disc_kernel<<<8192, 128, 0, stream>>>(h2, h2a, gbuf, gabuf, disc_W, disc_b,
                                          out + O_RET, out + O_RETA);

    // ---- copy h2 outputs (slots 0, 4, 5)
    copy_h2<<<2048, 256, 0, stream>>>(h2, h2a, out);
}